// Round 12
// baseline (822.962 us; speedup 1.0000x reference)
//
#include <hip/hip_runtime.h>
#include <math.h>

#define B 8
#define T 4096
#define D 512
#define H1 256
#define R 1024                      // B * NCH chunk-rows
#define BIDX_OFF ((size_t)B*T*D)          // 16777216
#define LOG_OFF  ((size_t)B*T*D + B*T)    // 16809984

typedef __attribute__((ext_vector_type(8))) short short8;
typedef __attribute__((ext_vector_type(4))) float f32x4;

__device__ inline unsigned short f2bf_hi(float f) {
  unsigned u = __float_as_uint(f);
  u += 0x7FFF + ((u >> 16) & 1);   // round-to-nearest-even bf16
  return (unsigned short)(u >> 16);
}
__device__ inline float bf2f(unsigned short b) {
  return __uint_as_float(((unsigned)b) << 16);
}
__device__ inline float sigm(float v) { return 1.f / (1.f + expf(-v)); }

// ---------------- prep: zero out, xhi bf16, W splits (gate-interleaved), W1 3-term, bsum ----------------
__global__ __launch_bounds__(256) void k_prep(const float* __restrict__ x,
                                              const float* __restrict__ Wih,
                                              const float* __restrict__ Whh,
                                              const float* __restrict__ bih,
                                              const float* __restrict__ bhh,
                                              const float* __restrict__ W1,
                                              float* __restrict__ out,
                                              unsigned short* __restrict__ xhi,
                                              unsigned short* __restrict__ WhhH,
                                              unsigned short* __restrict__ WhhL,
                                              unsigned short* __restrict__ WxH,
                                              float* __restrict__ bsum,
                                              unsigned short* __restrict__ W1t0,
                                              unsigned short* __restrict__ W1t1,
                                              unsigned short* __restrict__ W1t2) {
  int gid = blockIdx.x * 256 + threadIdx.x;   // 1,048,576 threads
  float4 z4 = make_float4(0.f, 0.f, 0.f, 0.f);
  // J0: zero padded output (64 MB)
  float4* o4 = (float4*)out;
#pragma unroll
  for (int i = 0; i < 4; ++i) o4[(size_t)i * 1048576 + gid] = z4;
  // J2: xhi bf16 (16 elems per thread)
  {
    const float* xs = x + (size_t)gid * 16;
    unsigned short hv[16];
#pragma unroll
    for (int q = 0; q < 4; ++q) {
      float4 v = *(const float4*)(xs + q * 4);
      hv[q * 4 + 0] = f2bf_hi(v.x); hv[q * 4 + 1] = f2bf_hi(v.y);
      hv[q * 4 + 2] = f2bf_hi(v.z); hv[q * 4 + 3] = f2bf_hi(v.w);
    }
    uint4 p0, p1;
    p0.x = (unsigned)hv[0] | ((unsigned)hv[1] << 16);  p0.y = (unsigned)hv[2] | ((unsigned)hv[3] << 16);
    p0.z = (unsigned)hv[4] | ((unsigned)hv[5] << 16);  p0.w = (unsigned)hv[6] | ((unsigned)hv[7] << 16);
    p1.x = (unsigned)hv[8] | ((unsigned)hv[9] << 16);  p1.y = (unsigned)hv[10] | ((unsigned)hv[11] << 16);
    p1.z = (unsigned)hv[12] | ((unsigned)hv[13] << 16); p1.w = (unsigned)hv[14] | ((unsigned)hv[15] << 16);
    *(uint4*)(xhi + (size_t)gid * 16) = p0;
    *(uint4*)(xhi + (size_t)gid * 16 + 8) = p1;
  }
  // J3: W splits, n' = 4d+g (gate-interleaved rows), K=512
  {
    int n = gid >> 9, k = gid & 511;
    int d = n >> 2, g = n & 3;
    size_t oo = (size_t)(g * 512 + d) * 512 + k;
    float wx = Wih[oo], wh = Whh[oo];
    WxH[(size_t)n * 512 + k] = f2bf_hi(wx);
    unsigned short hh = f2bf_hi(wh);
    WhhH[(size_t)n * 512 + k] = hh;
    WhhL[(size_t)n * 512 + k] = f2bf_hi(wh - bf2f(hh));
    if (k == 0) bsum[n] = bih[g * 512 + d] + bhh[g * 512 + d];
  }
  // J4: W1 3-term (8 elems per thread, first 16384 threads)
  if (gid < 16384) {
    int base = gid * 8;
    float4 a = *(const float4*)(W1 + base);
    float4 b = *(const float4*)(W1 + base + 4);
    float fv[8] = {a.x, a.y, a.z, a.w, b.x, b.y, b.z, b.w};
    unsigned short t0[8], t1[8], t2[8];
#pragma unroll
    for (int j = 0; j < 8; ++j) {
      unsigned short h0 = f2bf_hi(fv[j]);
      float r1 = fv[j] - bf2f(h0);
      unsigned short h1v = f2bf_hi(r1);
      float r2 = r1 - bf2f(h1v);
      t0[j] = h0; t1[j] = h1v; t2[j] = f2bf_hi(r2);
    }
    uint4 p0, p1, p2;
    p0.x = (unsigned)t0[0] | ((unsigned)t0[1] << 16); p0.y = (unsigned)t0[2] | ((unsigned)t0[3] << 16);
    p0.z = (unsigned)t0[4] | ((unsigned)t0[5] << 16); p0.w = (unsigned)t0[6] | ((unsigned)t0[7] << 16);
    p1.x = (unsigned)t1[0] | ((unsigned)t1[1] << 16); p1.y = (unsigned)t1[2] | ((unsigned)t1[3] << 16);
    p1.z = (unsigned)t1[4] | ((unsigned)t1[5] << 16); p1.w = (unsigned)t1[6] | ((unsigned)t1[7] << 16);
    p2.x = (unsigned)t2[0] | ((unsigned)t2[1] << 16); p2.y = (unsigned)t2[2] | ((unsigned)t2[3] << 16);
    p2.z = (unsigned)t2[4] | ((unsigned)t2[5] << 16); p2.w = (unsigned)t2[6] | ((unsigned)t2[7] << 16);
    *(uint4*)(W1t0 + base) = p0;
    *(uint4*)(W1t1 + base) = p1;
    *(uint4*)(W1t2 + base) = p2;
  }
}

// ---------------- boundary GEMM1 via MFMA, 3-term split (r3 version, 75µs proven) ----------------
__global__ __launch_bounds__(256) void k_bnd1(const float* __restrict__ x,
                                              const unsigned short* __restrict__ T0,
                                              const unsigned short* __restrict__ T1,
                                              const unsigned short* __restrict__ T2,
                                              const float* __restrict__ b1,
                                              float* __restrict__ h1out) {
  __shared__ unsigned short A0[64][48], A1[64][48], A2[64][48];
  __shared__ unsigned short B0[64][48], B1[64][48], B2[64][48];
  int bm = blockIdx.x, bnn = blockIdx.y;
  int tid = threadIdx.x;
  int arow = tid >> 2, ak0 = (tid & 3) * 8;
  const float* xrow = x + (size_t)(bm * 64 + arow) * 512;
  size_t wro = (size_t)(bnn * 64 + arow) * 512;

  int w = tid >> 6, l = tid & 63;
  int wm = w >> 1, wn = w & 1;
  int lrow = l & 15, lk = (l >> 4) * 8;

  f32x4 acc[2][2];
#pragma unroll
  for (int i = 0; i < 2; ++i)
#pragma unroll
    for (int j = 0; j < 2; ++j) acc[i][j] = (f32x4)(0.f);

  for (int kb = 0; kb < 512; kb += 32) {
    float4 a0v = *(const float4*)(xrow + kb + ak0);
    float4 a1v = *(const float4*)(xrow + kb + ak0 + 4);
    float fv[8] = {a0v.x, a0v.y, a0v.z, a0v.w, a1v.x, a1v.y, a1v.z, a1v.w};
    unsigned short s0[8], s1[8], s2[8];
#pragma unroll
    for (int j = 0; j < 8; ++j) {
      unsigned short h0 = f2bf_hi(fv[j]);
      float r1 = fv[j] - bf2f(h0);
      unsigned short h1v = f2bf_hi(r1);
      float r2 = r1 - bf2f(h1v);
      s0[j] = h0; s1[j] = h1v; s2[j] = f2bf_hi(r2);
    }
    uint4 p;
    p.x = (unsigned)s0[0] | ((unsigned)s0[1] << 16); p.y = (unsigned)s0[2] | ((unsigned)s0[3] << 16);
    p.z = (unsigned)s0[4] | ((unsigned)s0[5] << 16); p.w = (unsigned)s0[6] | ((unsigned)s0[7] << 16);
    *(uint4*)&A0[arow][ak0] = p;
    p.x = (unsigned)s1[0] | ((unsigned)s1[1] << 16); p.y = (unsigned)s1[2] | ((unsigned)s1[3] << 16);
    p.z = (unsigned)s1[4] | ((unsigned)s1[5] << 16); p.w = (unsigned)s1[6] | ((unsigned)s1[7] << 16);
    *(uint4*)&A1[arow][ak0] = p;
    p.x = (unsigned)s2[0] | ((unsigned)s2[1] << 16); p.y = (unsigned)s2[2] | ((unsigned)s2[3] << 16);
    p.z = (unsigned)s2[4] | ((unsigned)s2[5] << 16); p.w = (unsigned)s2[6] | ((unsigned)s2[7] << 16);
    *(uint4*)&A2[arow][ak0] = p;

    *(uint4*)&B0[arow][ak0] = *(const uint4*)(T0 + wro + kb + ak0);
    *(uint4*)&B1[arow][ak0] = *(const uint4*)(T1 + wro + kb + ak0);
    *(uint4*)&B2[arow][ak0] = *(const uint4*)(T2 + wro + kb + ak0);
    __syncthreads();

    short8 a0f[2], a1f[2], a2f[2], b0f[2], b1f[2], b2f[2];
#pragma unroll
    for (int fi = 0; fi < 2; ++fi) {
      a0f[fi] = *(const short8*)&A0[wm * 32 + fi * 16 + lrow][lk];
      a1f[fi] = *(const short8*)&A1[wm * 32 + fi * 16 + lrow][lk];
      a2f[fi] = *(const short8*)&A2[wm * 32 + fi * 16 + lrow][lk];
      b0f[fi] = *(const short8*)&B0[wn * 32 + fi * 16 + lrow][lk];
      b1f[fi] = *(const short8*)&B1[wn * 32 + fi * 16 + lrow][lk];
      b2f[fi] = *(const short8*)&B2[wn * 32 + fi * 16 + lrow][lk];
    }
#pragma unroll
    for (int fi = 0; fi < 2; ++fi)
#pragma unroll
      for (int fj = 0; fj < 2; ++fj) {
        acc[fi][fj] = __builtin_amdgcn_mfma_f32_16x16x32_bf16(a0f[fi], b0f[fj], acc[fi][fj], 0, 0, 0);
        acc[fi][fj] = __builtin_amdgcn_mfma_f32_16x16x32_bf16(a0f[fi], b1f[fj], acc[fi][fj], 0, 0, 0);
        acc[fi][fj] = __builtin_amdgcn_mfma_f32_16x16x32_bf16(a1f[fi], b0f[fj], acc[fi][fj], 0, 0, 0);
        acc[fi][fj] = __builtin_amdgcn_mfma_f32_16x16x32_bf16(a1f[fi], b1f[fj], acc[fi][fj], 0, 0, 0);
        acc[fi][fj] = __builtin_amdgcn_mfma_f32_16x16x32_bf16(a0f[fi], b2f[fj], acc[fi][fj], 0, 0, 0);
        acc[fi][fj] = __builtin_amdgcn_mfma_f32_16x16x32_bf16(a2f[fi], b0f[fj], acc[fi][fj], 0, 0, 0);
      }
    __syncthreads();
  }
#pragma unroll
  for (int fi = 0; fi < 2; ++fi)
#pragma unroll
    for (int fj = 0; fj < 2; ++fj) {
      int rrow = bm * 64 + wm * 32 + fi * 16 + (l >> 4) * 4;
      int rcol = bnn * 64 + wn * 32 + fj * 16 + lrow;
      float bv = b1[rcol];
#pragma unroll
      for (int reg = 0; reg < 4; ++reg) {
        float v = acc[fi][fj][reg] + bv;
        float ge = 0.5f * v * (1.0f + erff(v * 0.70710678118654752f));
        h1out[(size_t)(rrow + reg) * H1 + rcol] = ge;
      }
    }
}

// ---------------- logits + flags (f32 exact path) ----------------
__global__ __launch_bounds__(256) void k_log(const float* __restrict__ h1,
                                             const float* __restrict__ W2,
                                             const float* __restrict__ b2,
                                             float* __restrict__ out,
                                             unsigned char* __restrict__ flags) {
  int tid = threadIdx.x;
  int row = blockIdx.x * 32 + (tid >> 3);
  int part = tid & 7;
  const float* hr = h1 + (size_t)row * H1 + part * 32;
  const float* w0 = W2 + part * 32;
  const float* w1 = W2 + H1 + part * 32;
  float s0 = 0.f, s1 = 0.f;
#pragma unroll
  for (int q = 0; q < 8; ++q) {
    float4 hv = *(const float4*)(hr + q * 4);
    float4 w0v = *(const float4*)(w0 + q * 4);
    float4 w1v = *(const float4*)(w1 + q * 4);
    s0 = fmaf(hv.x, w0v.x, fmaf(hv.y, w0v.y, fmaf(hv.z, w0v.z, fmaf(hv.w, w0v.w, s0))));
    s1 = fmaf(hv.x, w1v.x, fmaf(hv.y, w1v.y, fmaf(hv.z, w1v.z, fmaf(hv.w, w1v.w, s1))));
  }
#pragma unroll
  for (int off = 4; off >= 1; off >>= 1) {
    s0 += __shfl_xor(s0, off);
    s1 += __shfl_xor(s1, off);
  }
  if (part == 0) {
    float l0 = s0 + b2[0], l1 = s1 + b2[1];
    out[LOG_OFF + (size_t)row * 2]     = l0;
    out[LOG_OFF + (size_t)row * 2 + 1] = l1;
    int t = row & (T - 1);
    bool forced = (((t & 31) == 0) && t != 0) || (t == T - 1);
    flags[row] = (forced || (l1 > l0)) ? 1 : 0;
  }
}

// ---------------- per-batch segmentation scan ----------------
__global__ __launch_bounds__(256) void k_seg(unsigned char* __restrict__ flags,
                                             int* __restrict__ segidx,
                                             int* __restrict__ counts,
                                             float* __restrict__ out) {
  int b = blockIdx.x, tid = threadIdx.x;
  __shared__ int sc[256];
  const int PER = T / 256;
  int base = tid * PER;
  bool em[PER];
  unsigned char prev = (tid == 0) ? 0 : (unsigned char)(flags[b * T + base - 1] & 1);
  int cnt = 0;
  for (int i = 0; i < PER; ++i) {
    int t = base + i;
    unsigned char cur = flags[b * T + t] & 1;
    bool reset = (t == 0) || (prev != 0);
    bool e = (cur != 0) && !reset;
    em[i] = e;
    cnt += e ? 1 : 0;
    flags[b * T + t] = (unsigned char)(cur | (reset ? 2 : 0) | (e ? 4 : 0));
    prev = cur;
  }
  sc[tid] = cnt;
  __syncthreads();
  for (int off = 1; off < 256; off <<= 1) {
    int v = (tid >= off) ? sc[tid - off] : 0;
    __syncthreads();
    sc[tid] += v;
    __syncthreads();
  }
  int total = sc[255];
  int run = sc[tid] - cnt;
  for (int i = 0; i < PER; ++i) {
    if (em[i]) { segidx[b * T + base + i] = run; run++; }
  }
  for (int j = tid; j < T; j += 256) out[BIDX_OFF + (size_t)b * T + j] = -1.0f;
  __syncthreads();
  run = sc[tid] - cnt;
  for (int i = 0; i < PER; ++i) {
    if (em[i]) { out[BIDX_OFF + (size_t)b * T + run] = (float)(base + i); run++; }
  }
  if (tid == 0) counts[b] = total;
}

// ---- gx = xhi @ WxH^T, M=32768 N=2048 K=512, 128x128 tile, BK=32, 512 threads (r10, 131µs) ----
__global__ __launch_bounds__(512) void k_gx(const unsigned short* __restrict__ xhi,
                                            const unsigned short* __restrict__ WxH,
                                            unsigned short* __restrict__ gx) {
  __shared__ unsigned short As[128][40], Bs[128][40];
  __shared__ unsigned short Cs[64][136];
  int m0 = blockIdx.x * 128, n0 = blockIdx.y * 128;
  int tid = threadIdx.x;
  int row = tid >> 2, col0 = (tid & 3) * 8;
  const unsigned short* asrc = xhi + (size_t)(m0 + row) * 512 + col0;
  const unsigned short* bsrc = WxH + (size_t)(n0 + row) * 512 + col0;

  int w = tid >> 6, l = tid & 63;
  int wm = w >> 2, wn = w & 3;
  int lrow = l & 15, lk = (l >> 4) * 8;

  f32x4 acc[4][2];
#pragma unroll
  for (int i = 0; i < 4; ++i)
#pragma unroll
    for (int j = 0; j < 2; ++j) acc[i][j] = (f32x4)(0.f);

  uint4 rA = *(const uint4*)asrc;
  uint4 rB = *(const uint4*)bsrc;

  for (int it = 0; it < 16; ++it) {
    *(uint4*)&As[row][col0] = rA;
    *(uint4*)&Bs[row][col0] = rB;
    __syncthreads();
    if (it < 15) {
      int ko = (it + 1) * 32;
      rA = *(const uint4*)(asrc + ko);
      rB = *(const uint4*)(bsrc + ko);
    }
    short8 af[4], bf[2];
#pragma unroll
    for (int fi = 0; fi < 4; ++fi)
      af[fi] = *(const short8*)&As[wm * 64 + fi * 16 + lrow][lk];
#pragma unroll
    for (int fj = 0; fj < 2; ++fj)
      bf[fj] = *(const short8*)&Bs[wn * 32 + fj * 16 + lrow][lk];
#pragma unroll
    for (int fi = 0; fi < 4; ++fi)
#pragma unroll
      for (int fj = 0; fj < 2; ++fj)
        acc[fi][fj] = __builtin_amdgcn_mfma_f32_16x16x32_bf16(af[fi], bf[fj], acc[fi][fj], 0, 0, 0);
    __syncthreads();
  }

#pragma unroll
  for (int h = 0; h < 2; ++h) {
    if (wm == h) {
#pragma unroll
      for (int fi = 0; fi < 4; ++fi)
#pragma unroll
        for (int fj = 0; fj < 2; ++fj) {
          int lr = fi * 16 + (l >> 4) * 4;
          int lc = wn * 32 + fj * 16 + lrow;
#pragma unroll
          for (int reg = 0; reg < 4; ++reg)
            Cs[lr + reg][lc] = f2bf_hi(acc[fi][fj][reg]);
        }
    }
    __syncthreads();
    int crow = tid >> 3, c0 = (tid & 7) * 16;
    size_t gbase = (size_t)(m0 + h * 64 + crow) * 2048 + n0 + c0;
    *(uint4*)(gx + gbase)     = *(uint4*)&Cs[crow][c0];
    *(uint4*)(gx + gbase + 8) = *(uint4*)&Cs[crow][c0 + 8];
    __syncthreads();
  }
}

// ---- s=0 cell-only: H,C are zero -> gates = gx + bsum; writes H buf0 ----
__global__ __launch_bounds__(256) void k_cell0(const unsigned short* __restrict__ gx,
                                               const float* __restrict__ bsum,
                                               const unsigned char* __restrict__ flags,
                                               const int* __restrict__ segidx,
                                               unsigned short* __restrict__ Hhi,
                                               unsigned short* __restrict__ Hlo,
                                               float* __restrict__ Cb,
                                               float* __restrict__ out) {
  int id = blockIdx.x * 256 + threadIdx.x;   // 524288 = 1024 x 512
  int rr = id >> 9, d = id & 511;
  int ch = rr & 127, bb = rr >> 7;
  int t = ch ? (32 * ch + 1) : 0;
  uint2 gp = *(const uint2*)(gx + ((size_t)(bb * T + t) * 2048 + 4 * d));
  float4 bsv = *(const float4*)&bsum[4 * d];
  float gi_ = bf2f((unsigned short)(gp.x & 0xffff)) + bsv.x;
  float gz_ = bf2f((unsigned short)(gp.y & 0xffff)) + bsv.z;
  float go_ = bf2f((unsigned short)(gp.y >> 16)) + bsv.w;
  float c = sigm(gi_) * tanhf(gz_);
  float h = sigm(go_) * tanhf(c);
  unsigned char fl = flags[bb * T + t];
  if (fl & 4) {
    int si = segidx[bb * T + t];
    out[(size_t)(bb * T + si) * D + d] = h;
  }
  bool isb = (fl & 1) != 0;
  float he = isb ? 0.f : h;
  float ce = isb ? 0.f : c;
  Cb[(size_t)rr * D + d] = ce;
  unsigned short hh = f2bf_hi(he);
  Hhi[(size_t)rr * D + d] = hh;
  Hlo[(size_t)rr * D + d] = f2bf_hi(he - bf2f(hh));
}

// ---- per-step (s=1..31): H-only GEMM K=512 (3-product) + cell with gx ----
// BK=32, staging 20.5 KB, Ct ALIASED onto staging (guarded by final K-loop barrier)
// -> ~6-8 blocks/CU for latency hiding. Math identical to r11.
__global__ __launch_bounds__(256) void k_step2(const unsigned short* __restrict__ gx,
                                               const unsigned short* __restrict__ WhhH,
                                               const unsigned short* __restrict__ WhhL,
                                               const unsigned short* __restrict__ HhR,
                                               const unsigned short* __restrict__ HlR,
                                               unsigned short* __restrict__ HhW,
                                               unsigned short* __restrict__ HlW,
                                               float* __restrict__ Cb,
                                               const float* __restrict__ bsum,
                                               const unsigned char* __restrict__ flags,
                                               const int* __restrict__ segidx,
                                               float* __restrict__ out, int s) {
  __shared__ __align__(16) char smem[20480];
  unsigned short (*Ah)[40] = (unsigned short(*)[40])smem;             // 5120 B
  unsigned short (*Al)[40] = (unsigned short(*)[40])(smem + 5120);    // 5120 B
  unsigned short (*Bh)[40] = (unsigned short(*)[40])(smem + 10240);   // 5120 B
  unsigned short (*Bl)[40] = (unsigned short(*)[40])(smem + 15360);   // 5120 B
  float (*Ct)[68] = (float(*)[68])smem;                               // 17408 B alias

  int id = blockIdx.x;
  int bm = (id & 7) * 2 + (id >> 8);
  int bn = (id >> 3) & 31;
  int tid = threadIdx.x;
  int arow = tid >> 2, acol = (tid & 3) * 8;   // 64 rows x 32 k, 1 uint4/thread/array
  int ra = bm * 64 + arow;
  const unsigned short* ah_src = HhR + (size_t)ra * D;
  const unsigned short* al_src = HlR + (size_t)ra * D;
  const unsigned short* bh_src = WhhH + (size_t)(bn * 64 + arow) * D;
  const unsigned short* bl_src = WhhL + (size_t)(bn * 64 + arow) * D;

  int w = tid >> 6, l = tid & 63;
  int wm = w >> 1, wn = w & 1;
  int lrow = l & 15, lk = (l >> 4) * 8;

  f32x4 acc[2][2];
#pragma unroll
  for (int i = 0; i < 2; ++i)
#pragma unroll
    for (int j = 0; j < 2; ++j) acc[i][j] = (f32x4)(0.f);

  uint4 rAh = *(const uint4*)(ah_src + acol);
  uint4 rAl = *(const uint4*)(al_src + acol);
  uint4 rBh = *(const uint4*)(bh_src + acol);
  uint4 rBl = *(const uint4*)(bl_src + acol);

  for (int kk = 0; kk < 16; ++kk) {
    *(uint4*)&Ah[arow][acol] = rAh;
    *(uint4*)&Al[arow][acol] = rAl;
    *(uint4*)&Bh[arow][acol] = rBh;
    *(uint4*)&Bl[arow][acol] = rBl;
    __syncthreads();
    if (kk < 15) {
      int ko = (kk + 1) * 32 + acol;
      rAh = *(const uint4*)(ah_src + ko);
      rAl = *(const uint4*)(al_src + ko);
      rBh = *(const uint4*)(bh_src + ko);
      rBl = *(const uint4*)(bl_src + ko);
    }
    short8 ah0 = *(const short8*)&Ah[wm * 32 + lrow][lk];
    short8 ah1 = *(const short8*)&Ah[wm * 32 + 16 + lrow][lk];
    short8 al0 = *(const short8*)&Al[wm * 32 + lrow][lk];
    short8 al1 = *(const short8*)&Al[wm * 32 + 16 + lrow][lk];
    short8 bh0 = *(const short8*)&Bh[wn * 32 + lrow][lk];
    short8 bh1 = *(const short8*)&Bh[wn * 32 + 16 + lrow][lk];
    short8 bl0 = *(const short8*)&Bl[wn * 32 + lrow][lk];
    short8 bl1 = *(const short8*)&Bl[wn * 32 + 16 + lrow][lk];
    acc[0][0] = __builtin_amdgcn_mfma_f32_16x16x32_bf16(ah0, bh0, acc[0][0], 0, 0, 0);
    acc[0][1] = __builtin_amdgcn_mfma_f32_16x16x32_bf16(ah0, bh1, acc[0][1], 0, 0, 0);
    acc[1][0] = __builtin_amdgcn_mfma_f32_16x16x32_bf16(ah1, bh0, acc[1][0], 0, 0, 0);
    acc[1][1] = __builtin_amdgcn_mfma_f32_16x16x32_bf16(ah1, bh1, acc[1][1], 0, 0, 0);
    acc[0][0] = __builtin_amdgcn_mfma_f32_16x16x32_bf16(ah0, bl0, acc[0][0], 0, 0, 0);
    acc[0][1] = __builtin_amdgcn_mfma_f32_16x16x32_bf16(ah0, bl1, acc[0][1], 0, 0, 0);
    acc[1][0] = __builtin_amdgcn_mfma_f32_16x16x32_bf16(ah1, bl0, acc[1][0], 0, 0, 0);
    acc[1][1] = __builtin_amdgcn_mfma_f32_16x16x32_bf16(ah1, bl1, acc[1][1], 0, 0, 0);
    acc[0][0] = __builtin_amdgcn_mfma_f32_16x16x32_bf16(al0, bh0, acc[0][0], 0, 0, 0);
    acc[0][1] = __builtin_amdgcn_mfma_f32_16x16x32_bf16(al0, bh1, acc[0][1], 0, 0, 0);
    acc[1][0] = __builtin_amdgcn_mfma_f32_16x16x32_bf16(al1, bh0, acc[1][0], 0, 0, 0);
    acc[1][1] = __builtin_amdgcn_mfma_f32_16x16x32_bf16(al1, bh1, acc[1][1], 0, 0, 0);
    __syncthreads();   // final iteration's barrier protects the Ct alias below
  }

  // stash acc tile to aliased Ct
#pragma unroll
  for (int fi = 0; fi < 2; ++fi)
#pragma unroll
    for (int fj = 0; fj < 2; ++fj) {
      int crow = wm * 32 + fi * 16 + (l >> 4) * 4;
      int ccol = wn * 32 + fj * 16 + lrow;
#pragma unroll
      for (int reg = 0; reg < 4; ++reg)
        Ct[crow + reg][ccol] = acc[fi][fj][reg];
    }
  __syncthreads();

  int d_loc = tid & 15, rb = tid >> 4;
  int d_g = bn * 16 + d_loc;
  float4 bsv = *(const float4*)&bsum[(size_t)4 * d_g];
#pragma unroll
  for (int j = 0; j < 4; ++j) {
    int r_loc = rb + 16 * j;
    int r = bm * 64 + r_loc;
    int ch = r & 127, bb = r >> 7;
    int len = (ch == 0) ? 33 : ((ch == 127) ? 31 : 32);
    if (s >= len) continue;
    int t = (ch ? (32 * ch + 1) : 0) + s;
    unsigned char fl = flags[bb * T + t];
    float4 g = *(float4*)&Ct[r_loc][4 * d_loc];
    uint2 gp = *(const uint2*)(gx + ((size_t)(bb * T + t) * 2048 + 4 * d_g));
    float gi = g.x + bsv.x + bf2f((unsigned short)(gp.x & 0xffff));
    float gf = g.y + bsv.y + bf2f((unsigned short)(gp.x >> 16));
    float gz = g.z + bsv.z + bf2f((unsigned short)(gp.y & 0xffff));
    float go = g.w + bsv.w + bf2f((unsigned short)(gp.y >> 16));
    float cp = Cb[(size_t)r * D + d_g];
    float c = sigm(gf) * cp + sigm(gi) * tanhf(gz);
    float h = sigm(go) * tanhf(c);
    if (fl & 4) {
      int si = segidx[bb * T + t];
      out[(size_t)(bb * T + si) * D + d_g] = h;
    }
    bool isb = (fl & 1) != 0;
    float he = isb ? 0.f : h;
    float ce = isb ? 0.f : c;
    Cb[(size_t)r * D + d_g] = ce;
    unsigned short hh = f2bf_hi(he);
    HhW[(size_t)r * D + d_g] = hh;
    HlW[(size_t)r * D + d_g] = f2bf_hi(he - bf2f(hh));
  }
}

// ---- s=32 tail: only ch=0 rows (8 rows); reads H buf1 (written at s=31) ----
__global__ __launch_bounds__(256) void k_tail(const unsigned short* __restrict__ gx,
                                              const unsigned short* __restrict__ WhhH,
                                              const unsigned short* __restrict__ WhhL,
                                              const unsigned short* __restrict__ Hhi,
                                              const unsigned short* __restrict__ Hlo,
                                              const float* __restrict__ Cb,
                                              const float* __restrict__ bsum,
                                              const unsigned char* __restrict__ flags,
                                              const int* __restrict__ segidx,
                                              float* __restrict__ out) {
  __shared__ float hsh[512];
  __shared__ float gsh[128][4];
  int bb = blockIdx.x >> 2, q = blockIdx.x & 3;
  int r = bb * 128;             // ch = 0
  int tid = threadIdx.x;
  for (int i = tid; i < 512; i += 256)
    hsh[i] = bf2f(Hhi[(size_t)r * 512 + i]) + bf2f(Hlo[(size_t)r * 512 + i]);
  __syncthreads();
  int dd_loc = tid >> 1;
  int dd = q * 128 + dd_loc;
  int pair = tid & 1;
#pragma unroll
  for (int gg = 0; gg < 2; ++gg) {
    int n = 4 * dd + 2 * pair + gg;
    const unsigned short* wh = WhhH + (size_t)n * 512;
    const unsigned short* wl = WhhL + (size_t)n * 512;
    float sacc = 0.f;
    for (int k = 0; k < 512; k += 8) {
      uint4 ph = *(const uint4*)(wh + k);
      uint4 pl = *(const uint4*)(wl + k);
      unsigned pu[4] = {ph.x, ph.y, ph.z, ph.w};
      unsigned lu[4] = {pl.x, pl.y, pl.z, pl.w};
#pragma unroll
      for (int j = 0; j < 4; ++j) {
        float w0 = bf2f((unsigned short)(pu[j] & 0xffff)) + bf2f((unsigned short)(lu[j] & 0xffff));
        float w1 = bf2f((unsigned short)(pu[j] >> 16)) + bf2f((unsigned short)(lu[j] >> 16));
        sacc = fmaf(w0, hsh[k + 2 * j], sacc);
        sacc = fmaf(w1, hsh[k + 2 * j + 1], sacc);
      }
    }
    unsigned short gxv = gx[(size_t)(bb * T + 32) * 2048 + n];
    gsh[dd_loc][2 * pair + gg] = sacc + bf2f(gxv) + bsum[n];
  }
  __syncthreads();
  if (pair == 0) {
    unsigned char fl = flags[bb * T + 32];
    float gi = gsh[dd_loc][0], gf = gsh[dd_loc][1], gz = gsh[dd_loc][2], go = gsh[dd_loc][3];
    float cp = Cb[(size_t)r * 512 + dd];
    float c = sigm(gf) * cp + sigm(gi) * tanhf(gz);
    float h = sigm(go) * tanhf(c);
    if (fl & 4) {
      int si = segidx[bb * T + 32];
      out[(size_t)(bb * T + si) * D + dd] = h;
    }
  }
}

// ---------------- fallback: no segments emitted -> mean over time ----------------
__global__ __launch_bounds__(256) void k_fb(const float* __restrict__ x,
                                            const int* __restrict__ counts,
                                            float* __restrict__ out) {
  int b = blockIdx.x;
  if (counts[b] != 0) return;
  int tid = threadIdx.x;
  for (int d = tid; d < D; d += 256) {
    float sum = 0.f;
    for (int t = 0; t < T; ++t) sum += x[(size_t)(b * T + t) * D + d];
    out[(size_t)(b * T) * D + d] = sum / (float)T;
  }
  if (tid == 0) out[BIDX_OFF + (size_t)b * T] = (float)(T - 1);
}

// ==================== LAUNCH ====================

extern "C" void kernel_launch(void* const* d_in, const int* in_sizes, int n_in,
                              void* d_out, int out_size, void* d_ws, size_t ws_size,
                              hipStream_t stream) {
  const float* x   = (const float*)d_in[0];
  const float* W1  = (const float*)d_in[1];
  const float* b1  = (const float*)d_in[2];
  const float* W2  = (const float*)d_in[3];
  const float* b2  = (const float*)d_in[4];
  const float* Wih = (const float*)d_in[5];
  const float* Whh = (const float*)d_in[6];
  const float* bih = (const float*)d_in[7];
  const float* bhh = (const float*)d_in[8];
  float* out = (float*)d_out;
  char* ws = (char*)d_ws;
  const size_t MB = 1 << 20;

  unsigned char* flags = (unsigned char*)(ws + 0);          // 32 KB
  int* counts = (int*)(ws + 32768);
  int* segidx = (int*)(ws + 65536);                         // 128 KB
  unsigned short* Hh0  = (unsigned short*)(ws + 1 * MB);    // 1 MB
  unsigned short* Hl0  = (unsigned short*)(ws + 2 * MB);    // 1 MB
  unsigned short* Hh1  = (unsigned short*)(ws + 3 * MB);    // 1 MB
  unsigned short* Hl1  = (unsigned short*)(ws + 4 * MB);    // 1 MB
  float* Cb            = (float*)(ws + 5 * MB);             // 2 MB
  unsigned short* WhhH = (unsigned short*)(ws + 7 * MB);    // 2 MB
  unsigned short* WhhL = (unsigned short*)(ws + 9 * MB);    // 2 MB
  unsigned short* WxH  = (unsigned short*)(ws + 11 * MB);   // 2 MB
  float* bsum          = (float*)(ws + 13 * MB);            // 8 KB
  unsigned short* W1t0 = (unsigned short*)(ws + 13 * MB + 262144);
  unsigned short* W1t1 = (unsigned short*)(ws + 13 * MB + 2 * 262144);
  unsigned short* W1t2 = (unsigned short*)(ws + 13 * MB + 3 * 262144);
  unsigned short* xhi  = (unsigned short*)(ws + 14 * MB);   // 32 MB
  unsigned short* gx   = (unsigned short*)(ws + 46 * MB);   // 128 MB -> ends 174 MB
  float* h1buf         = (float*)(ws + 46 * MB);            // 32 MB overlay on gx (dead before k_gx)

  hipLaunchKernelGGL(k_prep, dim3(4096), dim3(256), 0, stream,
                     x, Wih, Whh, bih, bhh, W1, out, xhi, WhhH, WhhL, WxH,
                     bsum, W1t0, W1t1, W1t2);
  hipLaunchKernelGGL(k_bnd1, dim3(512, 4), dim3(256), 0, stream, x, W1t0, W1t1, W1t2, b1, h1buf);
  hipLaunchKernelGGL(k_log, dim3(1024), dim3(256), 0, stream, h1buf, W2, b2, out, flags);
  hipLaunchKernelGGL(k_seg, dim3(8), dim3(256), 0, stream, flags, segidx, counts, out);
  hipLaunchKernelGGL(k_gx, dim3(256, 16), dim3(512), 0, stream, xhi, WxH, gx);
  hipLaunchKernelGGL(k_cell0, dim3(2048), dim3(256), 0, stream, gx, bsum, flags, segidx, Hh0, Hl0, Cb, out);
  for (int s = 1; s < 32; ++s) {
    const unsigned short* HhR = ((s - 1) & 1) ? Hh1 : Hh0;
    const unsigned short* HlR = ((s - 1) & 1) ? Hl1 : Hl0;
    unsigned short* HhW = (s & 1) ? Hh1 : Hh0;
    unsigned short* HlW = (s & 1) ? Hl1 : Hl0;
    hipLaunchKernelGGL(k_step2, dim3(512), dim3(256), 0, stream,
                       gx, WhhH, WhhL, HhR, HlR, HhW, HlW, Cb, bsum, flags, segidx, out, s);
  }
  hipLaunchKernelGGL(k_tail, dim3(32), dim3(256), 0, stream,
                     gx, WhhH, WhhL, Hh1, Hl1, Cb, bsum, flags, segidx, out);
  hipLaunchKernelGGL(k_fb, dim3(8), dim3(256), 0, stream, x, counts, out);
}

// Round 13
// 752.830 us; speedup vs baseline: 1.0932x; 1.0932x over previous
//
#include <hip/hip_runtime.h>
#include <math.h>

#define B 8
#define T 4096
#define D 512
#define H1 256
#define R 1024                      // B * NCH chunk-rows
#define BIDX_OFF ((size_t)B*T*D)          // 16777216
#define LOG_OFF  ((size_t)B*T*D + B*T)    // 16809984

typedef __attribute__((ext_vector_type(8))) short short8;
typedef __attribute__((ext_vector_type(4))) float f32x4;

__device__ inline unsigned short f2bf_hi(float f) {
  unsigned u = __float_as_uint(f);
  u += 0x7FFF + ((u >> 16) & 1);   // round-to-nearest-even bf16
  return (unsigned short)(u >> 16);
}
__device__ inline float bf2f(unsigned short b) {
  return __uint_as_float(((unsigned)b) << 16);
}
__device__ inline float sigm(float v) { return 1.f / (1.f + expf(-v)); }

// ---------------- prep: zero out, xhi bf16, W splits (gate-interleaved), W1 3-term, bsum ----------------
__global__ __launch_bounds__(256) void k_prep(const float* __restrict__ x,
                                              const float* __restrict__ Wih,
                                              const float* __restrict__ Whh,
                                              const float* __restrict__ bih,
                                              const float* __restrict__ bhh,
                                              const float* __restrict__ W1,
                                              float* __restrict__ out,
                                              unsigned short* __restrict__ xhi,
                                              unsigned short* __restrict__ WhhH,
                                              unsigned short* __restrict__ WhhL,
                                              unsigned short* __restrict__ WxH,
                                              float* __restrict__ bsum,
                                              unsigned short* __restrict__ W1t0,
                                              unsigned short* __restrict__ W1t1,
                                              unsigned short* __restrict__ W1t2) {
  int gid = blockIdx.x * 256 + threadIdx.x;   // 1,048,576 threads
  float4 z4 = make_float4(0.f, 0.f, 0.f, 0.f);
  // J0: zero padded output (64 MB)
  float4* o4 = (float4*)out;
#pragma unroll
  for (int i = 0; i < 4; ++i) o4[(size_t)i * 1048576 + gid] = z4;
  // J2: xhi bf16 (16 elems per thread)
  {
    const float* xs = x + (size_t)gid * 16;
    unsigned short hv[16];
#pragma unroll
    for (int q = 0; q < 4; ++q) {
      float4 v = *(const float4*)(xs + q * 4);
      hv[q * 4 + 0] = f2bf_hi(v.x); hv[q * 4 + 1] = f2bf_hi(v.y);
      hv[q * 4 + 2] = f2bf_hi(v.z); hv[q * 4 + 3] = f2bf_hi(v.w);
    }
    uint4 p0, p1;
    p0.x = (unsigned)hv[0] | ((unsigned)hv[1] << 16);  p0.y = (unsigned)hv[2] | ((unsigned)hv[3] << 16);
    p0.z = (unsigned)hv[4] | ((unsigned)hv[5] << 16);  p0.w = (unsigned)hv[6] | ((unsigned)hv[7] << 16);
    p1.x = (unsigned)hv[8] | ((unsigned)hv[9] << 16);  p1.y = (unsigned)hv[10] | ((unsigned)hv[11] << 16);
    p1.z = (unsigned)hv[12] | ((unsigned)hv[13] << 16); p1.w = (unsigned)hv[14] | ((unsigned)hv[15] << 16);
    *(uint4*)(xhi + (size_t)gid * 16) = p0;
    *(uint4*)(xhi + (size_t)gid * 16 + 8) = p1;
  }
  // J3: W splits, n' = 4d+g (gate-interleaved rows), K=512
  {
    int n = gid >> 9, k = gid & 511;
    int d = n >> 2, g = n & 3;
    size_t oo = (size_t)(g * 512 + d) * 512 + k;
    float wx = Wih[oo], wh = Whh[oo];
    WxH[(size_t)n * 512 + k] = f2bf_hi(wx);
    unsigned short hh = f2bf_hi(wh);
    WhhH[(size_t)n * 512 + k] = hh;
    WhhL[(size_t)n * 512 + k] = f2bf_hi(wh - bf2f(hh));
    if (k == 0) bsum[n] = bih[g * 512 + d] + bhh[g * 512 + d];
  }
  // J4: W1 3-term (8 elems per thread, first 16384 threads)
  if (gid < 16384) {
    int base = gid * 8;
    float4 a = *(const float4*)(W1 + base);
    float4 b = *(const float4*)(W1 + base + 4);
    float fv[8] = {a.x, a.y, a.z, a.w, b.x, b.y, b.z, b.w};
    unsigned short t0[8], t1[8], t2[8];
#pragma unroll
    for (int j = 0; j < 8; ++j) {
      unsigned short h0 = f2bf_hi(fv[j]);
      float r1 = fv[j] - bf2f(h0);
      unsigned short h1v = f2bf_hi(r1);
      float r2 = r1 - bf2f(h1v);
      t0[j] = h0; t1[j] = h1v; t2[j] = f2bf_hi(r2);
    }
    uint4 p0, p1, p2;
    p0.x = (unsigned)t0[0] | ((unsigned)t0[1] << 16); p0.y = (unsigned)t0[2] | ((unsigned)t0[3] << 16);
    p0.z = (unsigned)t0[4] | ((unsigned)t0[5] << 16); p0.w = (unsigned)t0[6] | ((unsigned)t0[7] << 16);
    p1.x = (unsigned)t1[0] | ((unsigned)t1[1] << 16); p1.y = (unsigned)t1[2] | ((unsigned)t1[3] << 16);
    p1.z = (unsigned)t1[4] | ((unsigned)t1[5] << 16); p1.w = (unsigned)t1[6] | ((unsigned)t1[7] << 16);
    p2.x = (unsigned)t2[0] | ((unsigned)t2[1] << 16); p2.y = (unsigned)t2[2] | ((unsigned)t2[3] << 16);
    p2.z = (unsigned)t2[4] | ((unsigned)t2[5] << 16); p2.w = (unsigned)t2[6] | ((unsigned)t2[7] << 16);
    *(uint4*)(W1t0 + base) = p0;
    *(uint4*)(W1t1 + base) = p1;
    *(uint4*)(W1t2 + base) = p2;
  }
}

// ---------------- boundary GEMM1 via MFMA, 3-term split (r3 version, 75µs proven) ----------------
__global__ __launch_bounds__(256) void k_bnd1(const float* __restrict__ x,
                                              const unsigned short* __restrict__ T0,
                                              const unsigned short* __restrict__ T1,
                                              const unsigned short* __restrict__ T2,
                                              const float* __restrict__ b1,
                                              float* __restrict__ h1out) {
  __shared__ unsigned short A0[64][48], A1[64][48], A2[64][48];
  __shared__ unsigned short B0[64][48], B1[64][48], B2[64][48];
  int bm = blockIdx.x, bnn = blockIdx.y;
  int tid = threadIdx.x;
  int arow = tid >> 2, ak0 = (tid & 3) * 8;
  const float* xrow = x + (size_t)(bm * 64 + arow) * 512;
  size_t wro = (size_t)(bnn * 64 + arow) * 512;

  int w = tid >> 6, l = tid & 63;
  int wm = w >> 1, wn = w & 1;
  int lrow = l & 15, lk = (l >> 4) * 8;

  f32x4 acc[2][2];
#pragma unroll
  for (int i = 0; i < 2; ++i)
#pragma unroll
    for (int j = 0; j < 2; ++j) acc[i][j] = (f32x4)(0.f);

  for (int kb = 0; kb < 512; kb += 32) {
    float4 a0v = *(const float4*)(xrow + kb + ak0);
    float4 a1v = *(const float4*)(xrow + kb + ak0 + 4);
    float fv[8] = {a0v.x, a0v.y, a0v.z, a0v.w, a1v.x, a1v.y, a1v.z, a1v.w};
    unsigned short s0[8], s1[8], s2[8];
#pragma unroll
    for (int j = 0; j < 8; ++j) {
      unsigned short h0 = f2bf_hi(fv[j]);
      float r1 = fv[j] - bf2f(h0);
      unsigned short h1v = f2bf_hi(r1);
      float r2 = r1 - bf2f(h1v);
      s0[j] = h0; s1[j] = h1v; s2[j] = f2bf_hi(r2);
    }
    uint4 p;
    p.x = (unsigned)s0[0] | ((unsigned)s0[1] << 16); p.y = (unsigned)s0[2] | ((unsigned)s0[3] << 16);
    p.z = (unsigned)s0[4] | ((unsigned)s0[5] << 16); p.w = (unsigned)s0[6] | ((unsigned)s0[7] << 16);
    *(uint4*)&A0[arow][ak0] = p;
    p.x = (unsigned)s1[0] | ((unsigned)s1[1] << 16); p.y = (unsigned)s1[2] | ((unsigned)s1[3] << 16);
    p.z = (unsigned)s1[4] | ((unsigned)s1[5] << 16); p.w = (unsigned)s1[6] | ((unsigned)s1[7] << 16);
    *(uint4*)&A1[arow][ak0] = p;
    p.x = (unsigned)s2[0] | ((unsigned)s2[1] << 16); p.y = (unsigned)s2[2] | ((unsigned)s2[3] << 16);
    p.z = (unsigned)s2[4] | ((unsigned)s2[5] << 16); p.w = (unsigned)s2[6] | ((unsigned)s2[7] << 16);
    *(uint4*)&A2[arow][ak0] = p;

    *(uint4*)&B0[arow][ak0] = *(const uint4*)(T0 + wro + kb + ak0);
    *(uint4*)&B1[arow][ak0] = *(const uint4*)(T1 + wro + kb + ak0);
    *(uint4*)&B2[arow][ak0] = *(const uint4*)(T2 + wro + kb + ak0);
    __syncthreads();

    short8 a0f[2], a1f[2], a2f[2], b0f[2], b1f[2], b2f[2];
#pragma unroll
    for (int fi = 0; fi < 2; ++fi) {
      a0f[fi] = *(const short8*)&A0[wm * 32 + fi * 16 + lrow][lk];
      a1f[fi] = *(const short8*)&A1[wm * 32 + fi * 16 + lrow][lk];
      a2f[fi] = *(const short8*)&A2[wm * 32 + fi * 16 + lrow][lk];
      b0f[fi] = *(const short8*)&B0[wn * 32 + fi * 16 + lrow][lk];
      b1f[fi] = *(const short8*)&B1[wn * 32 + fi * 16 + lrow][lk];
      b2f[fi] = *(const short8*)&B2[wn * 32 + fi * 16 + lrow][lk];
    }
#pragma unroll
    for (int fi = 0; fi < 2; ++fi)
#pragma unroll
      for (int fj = 0; fj < 2; ++fj) {
        acc[fi][fj] = __builtin_amdgcn_mfma_f32_16x16x32_bf16(a0f[fi], b0f[fj], acc[fi][fj], 0, 0, 0);
        acc[fi][fj] = __builtin_amdgcn_mfma_f32_16x16x32_bf16(a0f[fi], b1f[fj], acc[fi][fj], 0, 0, 0);
        acc[fi][fj] = __builtin_amdgcn_mfma_f32_16x16x32_bf16(a1f[fi], b0f[fj], acc[fi][fj], 0, 0, 0);
        acc[fi][fj] = __builtin_amdgcn_mfma_f32_16x16x32_bf16(a1f[fi], b1f[fj], acc[fi][fj], 0, 0, 0);
        acc[fi][fj] = __builtin_amdgcn_mfma_f32_16x16x32_bf16(a0f[fi], b2f[fj], acc[fi][fj], 0, 0, 0);
        acc[fi][fj] = __builtin_amdgcn_mfma_f32_16x16x32_bf16(a2f[fi], b0f[fj], acc[fi][fj], 0, 0, 0);
      }
    __syncthreads();
  }
#pragma unroll
  for (int fi = 0; fi < 2; ++fi)
#pragma unroll
    for (int fj = 0; fj < 2; ++fj) {
      int rrow = bm * 64 + wm * 32 + fi * 16 + (l >> 4) * 4;
      int rcol = bnn * 64 + wn * 32 + fj * 16 + lrow;
      float bv = b1[rcol];
#pragma unroll
      for (int reg = 0; reg < 4; ++reg) {
        float v = acc[fi][fj][reg] + bv;
        float ge = 0.5f * v * (1.0f + erff(v * 0.70710678118654752f));
        h1out[(size_t)(rrow + reg) * H1 + rcol] = ge;
      }
    }
}

// ---------------- logits + flags (f32 exact path) ----------------
__global__ __launch_bounds__(256) void k_log(const float* __restrict__ h1,
                                             const float* __restrict__ W2,
                                             const float* __restrict__ b2,
                                             float* __restrict__ out,
                                             unsigned char* __restrict__ flags) {
  int tid = threadIdx.x;
  int row = blockIdx.x * 32 + (tid >> 3);
  int part = tid & 7;
  const float* hr = h1 + (size_t)row * H1 + part * 32;
  const float* w0 = W2 + part * 32;
  const float* w1 = W2 + H1 + part * 32;
  float s0 = 0.f, s1 = 0.f;
#pragma unroll
  for (int q = 0; q < 8; ++q) {
    float4 hv = *(const float4*)(hr + q * 4);
    float4 w0v = *(const float4*)(w0 + q * 4);
    float4 w1v = *(const float4*)(w1 + q * 4);
    s0 = fmaf(hv.x, w0v.x, fmaf(hv.y, w0v.y, fmaf(hv.z, w0v.z, fmaf(hv.w, w0v.w, s0))));
    s1 = fmaf(hv.x, w1v.x, fmaf(hv.y, w1v.y, fmaf(hv.z, w1v.z, fmaf(hv.w, w1v.w, s1))));
  }
#pragma unroll
  for (int off = 4; off >= 1; off >>= 1) {
    s0 += __shfl_xor(s0, off);
    s1 += __shfl_xor(s1, off);
  }
  if (part == 0) {
    float l0 = s0 + b2[0], l1 = s1 + b2[1];
    out[LOG_OFF + (size_t)row * 2]     = l0;
    out[LOG_OFF + (size_t)row * 2 + 1] = l1;
    int t = row & (T - 1);
    bool forced = (((t & 31) == 0) && t != 0) || (t == T - 1);
    flags[row] = (forced || (l1 > l0)) ? 1 : 0;
  }
}

// ---------------- per-batch segmentation scan ----------------
__global__ __launch_bounds__(256) void k_seg(unsigned char* __restrict__ flags,
                                             int* __restrict__ segidx,
                                             int* __restrict__ counts,
                                             float* __restrict__ out) {
  int b = blockIdx.x, tid = threadIdx.x;
  __shared__ int sc[256];
  const int PER = T / 256;
  int base = tid * PER;
  bool em[PER];
  unsigned char prev = (tid == 0) ? 0 : (unsigned char)(flags[b * T + base - 1] & 1);
  int cnt = 0;
  for (int i = 0; i < PER; ++i) {
    int t = base + i;
    unsigned char cur = flags[b * T + t] & 1;
    bool reset = (t == 0) || (prev != 0);
    bool e = (cur != 0) && !reset;
    em[i] = e;
    cnt += e ? 1 : 0;
    flags[b * T + t] = (unsigned char)(cur | (reset ? 2 : 0) | (e ? 4 : 0));
    prev = cur;
  }
  sc[tid] = cnt;
  __syncthreads();
  for (int off = 1; off < 256; off <<= 1) {
    int v = (tid >= off) ? sc[tid - off] : 0;
    __syncthreads();
    sc[tid] += v;
    __syncthreads();
  }
  int total = sc[255];
  int run = sc[tid] - cnt;
  for (int i = 0; i < PER; ++i) {
    if (em[i]) { segidx[b * T + base + i] = run; run++; }
  }
  for (int j = tid; j < T; j += 256) out[BIDX_OFF + (size_t)b * T + j] = -1.0f;
  __syncthreads();
  run = sc[tid] - cnt;
  for (int i = 0; i < PER; ++i) {
    if (em[i]) { out[BIDX_OFF + (size_t)b * T + run] = (float)(base + i); run++; }
  }
  if (tid == 0) counts[b] = total;
}

// ---- gx = xhi @ WxH^T, M=32768 N=2048 K=512, 128x128 tile, BK=32, 512 threads (r10, 131µs) ----
__global__ __launch_bounds__(512) void k_gx(const unsigned short* __restrict__ xhi,
                                            const unsigned short* __restrict__ WxH,
                                            unsigned short* __restrict__ gx) {
  __shared__ unsigned short As[128][40], Bs[128][40];
  __shared__ unsigned short Cs[64][136];
  int m0 = blockIdx.x * 128, n0 = blockIdx.y * 128;
  int tid = threadIdx.x;
  int row = tid >> 2, col0 = (tid & 3) * 8;
  const unsigned short* asrc = xhi + (size_t)(m0 + row) * 512 + col0;
  const unsigned short* bsrc = WxH + (size_t)(n0 + row) * 512 + col0;

  int w = tid >> 6, l = tid & 63;
  int wm = w >> 2, wn = w & 3;
  int lrow = l & 15, lk = (l >> 4) * 8;

  f32x4 acc[4][2];
#pragma unroll
  for (int i = 0; i < 4; ++i)
#pragma unroll
    for (int j = 0; j < 2; ++j) acc[i][j] = (f32x4)(0.f);

  uint4 rA = *(const uint4*)asrc;
  uint4 rB = *(const uint4*)bsrc;

  for (int it = 0; it < 16; ++it) {
    *(uint4*)&As[row][col0] = rA;
    *(uint4*)&Bs[row][col0] = rB;
    __syncthreads();
    if (it < 15) {
      int ko = (it + 1) * 32;
      rA = *(const uint4*)(asrc + ko);
      rB = *(const uint4*)(bsrc + ko);
    }
    short8 af[4], bf[2];
#pragma unroll
    for (int fi = 0; fi < 4; ++fi)
      af[fi] = *(const short8*)&As[wm * 64 + fi * 16 + lrow][lk];
#pragma unroll
    for (int fj = 0; fj < 2; ++fj)
      bf[fj] = *(const short8*)&Bs[wn * 32 + fj * 16 + lrow][lk];
#pragma unroll
    for (int fi = 0; fi < 4; ++fi)
#pragma unroll
      for (int fj = 0; fj < 2; ++fj)
        acc[fi][fj] = __builtin_amdgcn_mfma_f32_16x16x32_bf16(af[fi], bf[fj], acc[fi][fj], 0, 0, 0);
    __syncthreads();
  }

#pragma unroll
  for (int h = 0; h < 2; ++h) {
    if (wm == h) {
#pragma unroll
      for (int fi = 0; fi < 4; ++fi)
#pragma unroll
        for (int fj = 0; fj < 2; ++fj) {
          int lr = fi * 16 + (l >> 4) * 4;
          int lc = wn * 32 + fj * 16 + lrow;
#pragma unroll
          for (int reg = 0; reg < 4; ++reg)
            Cs[lr + reg][lc] = f2bf_hi(acc[fi][fj][reg]);
        }
    }
    __syncthreads();
    int crow = tid >> 3, c0 = (tid & 7) * 16;
    size_t gbase = (size_t)(m0 + h * 64 + crow) * 2048 + n0 + c0;
    *(uint4*)(gx + gbase)     = *(uint4*)&Cs[crow][c0];
    *(uint4*)(gx + gbase + 8) = *(uint4*)&Cs[crow][c0 + 8];
    __syncthreads();
  }
}

// ---- s=0 cell-only: H,C are zero -> gates = gx + bsum; writes H buf0 ----
__global__ __launch_bounds__(256) void k_cell0(const unsigned short* __restrict__ gx,
                                               const float* __restrict__ bsum,
                                               const unsigned char* __restrict__ flags,
                                               const int* __restrict__ segidx,
                                               unsigned short* __restrict__ Hhi,
                                               unsigned short* __restrict__ Hlo,
                                               float* __restrict__ Cb,
                                               float* __restrict__ out) {
  int id = blockIdx.x * 256 + threadIdx.x;   // 524288 = 1024 x 512
  int rr = id >> 9, d = id & 511;
  int ch = rr & 127, bb = rr >> 7;
  int t = ch ? (32 * ch + 1) : 0;
  uint2 gp = *(const uint2*)(gx + ((size_t)(bb * T + t) * 2048 + 4 * d));
  float4 bsv = *(const float4*)&bsum[4 * d];
  float gi_ = bf2f((unsigned short)(gp.x & 0xffff)) + bsv.x;
  float gz_ = bf2f((unsigned short)(gp.y & 0xffff)) + bsv.z;
  float go_ = bf2f((unsigned short)(gp.y >> 16)) + bsv.w;
  float c = sigm(gi_) * tanhf(gz_);
  float h = sigm(go_) * tanhf(c);
  unsigned char fl = flags[bb * T + t];
  if (fl & 4) {
    int si = segidx[bb * T + t];
    out[(size_t)(bb * T + si) * D + d] = h;
  }
  bool isb = (fl & 1) != 0;
  float he = isb ? 0.f : h;
  float ce = isb ? 0.f : c;
  Cb[(size_t)rr * D + d] = ce;
  unsigned short hh = f2bf_hi(he);
  Hhi[(size_t)rr * D + d] = hh;
  Hlo[(size_t)rr * D + d] = f2bf_hi(he - bf2f(hh));
}

// ---- per-step (s=1..31): H-only GEMM K=512 (3-product) + cell with gx ----
// r11 structure (BK=64, 8 K-iterations, 256 thr, 64x64, grid 512) with ONE change:
// Ct aliased onto dead staging LDS -> 36.9 KB -> 4 blocks/CU (was 2).
__global__ __launch_bounds__(256) void k_step2(const unsigned short* __restrict__ gx,
                                               const unsigned short* __restrict__ WhhH,
                                               const unsigned short* __restrict__ WhhL,
                                               const unsigned short* __restrict__ HhR,
                                               const unsigned short* __restrict__ HlR,
                                               unsigned short* __restrict__ HhW,
                                               unsigned short* __restrict__ HlW,
                                               float* __restrict__ Cb,
                                               const float* __restrict__ bsum,
                                               const unsigned char* __restrict__ flags,
                                               const int* __restrict__ segidx,
                                               float* __restrict__ out, int s) {
  __shared__ __align__(16) char smem[36864];
  unsigned short (*Ah)[72] = (unsigned short(*)[72])smem;             // 9216 B
  unsigned short (*Al)[72] = (unsigned short(*)[72])(smem + 9216);    // 9216 B
  unsigned short (*Bh)[72] = (unsigned short(*)[72])(smem + 18432);   // 9216 B
  unsigned short (*Bl)[72] = (unsigned short(*)[72])(smem + 27648);   // 9216 B
  float (*Ct)[68] = (float(*)[68])smem;                               // 17408 B alias (dead staging)

  int id = blockIdx.x;
  int bm = (id & 7) * 2 + (id >> 8);
  int bn = (id >> 3) & 31;
  int tid = threadIdx.x;
  int row = tid >> 2, col0 = (tid & 3) * 16;
  int ra = bm * 64 + row;
  const unsigned short* ah_src = HhR + (size_t)ra * D;
  const unsigned short* al_src = HlR + (size_t)ra * D;
  const unsigned short* bh_src = WhhH + (size_t)(bn * 64 + row) * D;
  const unsigned short* bl_src = WhhL + (size_t)(bn * 64 + row) * D;

  int w = tid >> 6, l = tid & 63;
  int wm = w >> 1, wn = w & 1;
  int lrow = l & 15, lk = (l >> 4) * 8;

  f32x4 acc[2][2];
#pragma unroll
  for (int i = 0; i < 2; ++i)
#pragma unroll
    for (int j = 0; j < 2; ++j) acc[i][j] = (f32x4)(0.f);

  uint4 rAh0 = *(const uint4*)(ah_src + col0), rAh1 = *(const uint4*)(ah_src + col0 + 8);
  uint4 rAl0 = *(const uint4*)(al_src + col0), rAl1 = *(const uint4*)(al_src + col0 + 8);
  uint4 rBh0 = *(const uint4*)(bh_src + col0), rBh1 = *(const uint4*)(bh_src + col0 + 8);
  uint4 rBl0 = *(const uint4*)(bl_src + col0), rBl1 = *(const uint4*)(bl_src + col0 + 8);

  for (int kk = 0; kk < 8; ++kk) {
    *(uint4*)&Ah[row][col0] = rAh0;  *(uint4*)&Ah[row][col0 + 8] = rAh1;
    *(uint4*)&Al[row][col0] = rAl0;  *(uint4*)&Al[row][col0 + 8] = rAl1;
    *(uint4*)&Bh[row][col0] = rBh0;  *(uint4*)&Bh[row][col0 + 8] = rBh1;
    *(uint4*)&Bl[row][col0] = rBl0;  *(uint4*)&Bl[row][col0 + 8] = rBl1;
    __syncthreads();
    if (kk < 7) {
      int ko = (kk + 1) * 64 + col0;
      rAh0 = *(const uint4*)(ah_src + ko); rAh1 = *(const uint4*)(ah_src + ko + 8);
      rAl0 = *(const uint4*)(al_src + ko); rAl1 = *(const uint4*)(al_src + ko + 8);
      rBh0 = *(const uint4*)(bh_src + ko); rBh1 = *(const uint4*)(bh_src + ko + 8);
      rBl0 = *(const uint4*)(bl_src + ko); rBl1 = *(const uint4*)(bl_src + ko + 8);
    }
#pragma unroll
    for (int ks = 0; ks < 2; ++ks) {
      short8 ah0 = *(const short8*)&Ah[wm * 32 + lrow][ks * 32 + lk];
      short8 ah1 = *(const short8*)&Ah[wm * 32 + 16 + lrow][ks * 32 + lk];
      short8 al0 = *(const short8*)&Al[wm * 32 + lrow][ks * 32 + lk];
      short8 al1 = *(const short8*)&Al[wm * 32 + 16 + lrow][ks * 32 + lk];
      short8 bh0 = *(const short8*)&Bh[wn * 32 + lrow][ks * 32 + lk];
      short8 bh1 = *(const short8*)&Bh[wn * 32 + 16 + lrow][ks * 32 + lk];
      short8 bl0 = *(const short8*)&Bl[wn * 32 + lrow][ks * 32 + lk];
      short8 bl1 = *(const short8*)&Bl[wn * 32 + 16 + lrow][ks * 32 + lk];
      acc[0][0] = __builtin_amdgcn_mfma_f32_16x16x32_bf16(ah0, bh0, acc[0][0], 0, 0, 0);
      acc[0][1] = __builtin_amdgcn_mfma_f32_16x16x32_bf16(ah0, bh1, acc[0][1], 0, 0, 0);
      acc[1][0] = __builtin_amdgcn_mfma_f32_16x16x32_bf16(ah1, bh0, acc[1][0], 0, 0, 0);
      acc[1][1] = __builtin_amdgcn_mfma_f32_16x16x32_bf16(ah1, bh1, acc[1][1], 0, 0, 0);
      acc[0][0] = __builtin_amdgcn_mfma_f32_16x16x32_bf16(ah0, bl0, acc[0][0], 0, 0, 0);
      acc[0][1] = __builtin_amdgcn_mfma_f32_16x16x32_bf16(ah0, bl1, acc[0][1], 0, 0, 0);
      acc[1][0] = __builtin_amdgcn_mfma_f32_16x16x32_bf16(ah1, bl0, acc[1][0], 0, 0, 0);
      acc[1][1] = __builtin_amdgcn_mfma_f32_16x16x32_bf16(ah1, bl1, acc[1][1], 0, 0, 0);
      acc[0][0] = __builtin_amdgcn_mfma_f32_16x16x32_bf16(al0, bh0, acc[0][0], 0, 0, 0);
      acc[0][1] = __builtin_amdgcn_mfma_f32_16x16x32_bf16(al0, bh1, acc[0][1], 0, 0, 0);
      acc[1][0] = __builtin_amdgcn_mfma_f32_16x16x32_bf16(al1, bh0, acc[1][0], 0, 0, 0);
      acc[1][1] = __builtin_amdgcn_mfma_f32_16x16x32_bf16(al1, bh1, acc[1][1], 0, 0, 0);
    }
    __syncthreads();   // final iteration's barrier protects the Ct alias below
  }

  // stash acc tile into aliased Ct (all staging reads completed before last barrier)
#pragma unroll
  for (int fi = 0; fi < 2; ++fi)
#pragma unroll
    for (int fj = 0; fj < 2; ++fj) {
      int crow = wm * 32 + fi * 16 + (l >> 4) * 4;
      int ccol = wn * 32 + fj * 16 + lrow;
#pragma unroll
      for (int reg = 0; reg < 4; ++reg)
        Ct[crow + reg][ccol] = acc[fi][fj][reg];
    }
  __syncthreads();

  int d_loc = tid & 15, rb = tid >> 4;
  int d_g = bn * 16 + d_loc;
  float4 bsv = *(const float4*)&bsum[(size_t)4 * d_g];
#pragma unroll
  for (int j = 0; j < 4; ++j) {
    int r_loc = rb + 16 * j;
    int r = bm * 64 + r_loc;
    int ch = r & 127, bb = r >> 7;
    int len = (ch == 0) ? 33 : ((ch == 127) ? 31 : 32);
    if (s >= len) continue;
    int t = (ch ? (32 * ch + 1) : 0) + s;
    unsigned char fl = flags[bb * T + t];
    float4 g = *(float4*)&Ct[r_loc][4 * d_loc];
    uint2 gp = *(const uint2*)(gx + ((size_t)(bb * T + t) * 2048 + 4 * d_g));
    float gi = g.x + bsv.x + bf2f((unsigned short)(gp.x & 0xffff));
    float gf = g.y + bsv.y + bf2f((unsigned short)(gp.x >> 16));
    float gz = g.z + bsv.z + bf2f((unsigned short)(gp.y & 0xffff));
    float go = g.w + bsv.w + bf2f((unsigned short)(gp.y >> 16));
    float cp = Cb[(size_t)r * D + d_g];
    float c = sigm(gf) * cp + sigm(gi) * tanhf(gz);
    float h = sigm(go) * tanhf(c);
    if (fl & 4) {
      int si = segidx[bb * T + t];
      out[(size_t)(bb * T + si) * D + d_g] = h;
    }
    bool isb = (fl & 1) != 0;
    float he = isb ? 0.f : h;
    float ce = isb ? 0.f : c;
    Cb[(size_t)r * D + d_g] = ce;
    unsigned short hh = f2bf_hi(he);
    HhW[(size_t)r * D + d_g] = hh;
    HlW[(size_t)r * D + d_g] = f2bf_hi(he - bf2f(hh));
  }
}

// ---- s=32 tail: only ch=0 rows (8 rows); reads H buf1 (written at s=31) ----
__global__ __launch_bounds__(256) void k_tail(const unsigned short* __restrict__ gx,
                                              const unsigned short* __restrict__ WhhH,
                                              const unsigned short* __restrict__ WhhL,
                                              const unsigned short* __restrict__ Hhi,
                                              const unsigned short* __restrict__ Hlo,
                                              const float* __restrict__ Cb,
                                              const float* __restrict__ bsum,
                                              const unsigned char* __restrict__ flags,
                                              const int* __restrict__ segidx,
                                              float* __restrict__ out) {
  __shared__ float hsh[512];
  __shared__ float gsh[128][4];
  int bb = blockIdx.x >> 2, q = blockIdx.x & 3;
  int r = bb * 128;             // ch = 0
  int tid = threadIdx.x;
  for (int i = tid; i < 512; i += 256)
    hsh[i] = bf2f(Hhi[(size_t)r * 512 + i]) + bf2f(Hlo[(size_t)r * 512 + i]);
  __syncthreads();
  int dd_loc = tid >> 1;
  int dd = q * 128 + dd_loc;
  int pair = tid & 1;
#pragma unroll
  for (int gg = 0; gg < 2; ++gg) {
    int n = 4 * dd + 2 * pair + gg;
    const unsigned short* wh = WhhH + (size_t)n * 512;
    const unsigned short* wl = WhhL + (size_t)n * 512;
    float sacc = 0.f;
    for (int k = 0; k < 512; k += 8) {
      uint4 ph = *(const uint4*)(wh + k);
      uint4 pl = *(const uint4*)(wl + k);
      unsigned pu[4] = {ph.x, ph.y, ph.z, ph.w};
      unsigned lu[4] = {pl.x, pl.y, pl.z, pl.w};
#pragma unroll
      for (int j = 0; j < 4; ++j) {
        float w0 = bf2f((unsigned short)(pu[j] & 0xffff)) + bf2f((unsigned short)(lu[j] & 0xffff));
        float w1 = bf2f((unsigned short)(pu[j] >> 16)) + bf2f((unsigned short)(lu[j] >> 16));
        sacc = fmaf(w0, hsh[k + 2 * j], sacc);
        sacc = fmaf(w1, hsh[k + 2 * j + 1], sacc);
      }
    }
    unsigned short gxv = gx[(size_t)(bb * T + 32) * 2048 + n];
    gsh[dd_loc][2 * pair + gg] = sacc + bf2f(gxv) + bsum[n];
  }
  __syncthreads();
  if (pair == 0) {
    unsigned char fl = flags[bb * T + 32];
    float gi = gsh[dd_loc][0], gf = gsh[dd_loc][1], gz = gsh[dd_loc][2], go = gsh[dd_loc][3];
    float cp = Cb[(size_t)r * 512 + dd];
    float c = sigm(gf) * cp + sigm(gi) * tanhf(gz);
    float h = sigm(go) * tanhf(c);
    if (fl & 4) {
      int si = segidx[bb * T + 32];
      out[(size_t)(bb * T + si) * D + dd] = h;
    }
  }
}

// ---------------- fallback: no segments emitted -> mean over time ----------------
__global__ __launch_bounds__(256) void k_fb(const float* __restrict__ x,
                                            const int* __restrict__ counts,
                                            float* __restrict__ out) {
  int b = blockIdx.x;
  if (counts[b] != 0) return;
  int tid = threadIdx.x;
  for (int d = tid; d < D; d += 256) {
    float sum = 0.f;
    for (int t = 0; t < T; ++t) sum += x[(size_t)(b * T + t) * D + d];
    out[(size_t)(b * T) * D + d] = sum / (float)T;
  }
  if (tid == 0) out[BIDX_OFF + (size_t)b * T] = (float)(T - 1);
}

// ==================== LAUNCH ====================

extern "C" void kernel_launch(void* const* d_in, const int* in_sizes, int n_in,
                              void* d_out, int out_size, void* d_ws, size_t ws_size,
                              hipStream_t stream) {
  const float* x   = (const float*)d_in[0];
  const float* W1  = (const float*)d_in[1];
  const float* b1  = (const float*)d_in[2];
  const float* W2  = (const float*)d_in[3];
  const float* b2  = (const float*)d_in[4];
  const float* Wih = (const float*)d_in[5];
  const float* Whh = (const float*)d_in[6];
  const float* bih = (const float*)d_in[7];
  const float* bhh = (const float*)d_in[8];
  float* out = (float*)d_out;
  char* ws = (char*)d_ws;
  const size_t MB = 1 << 20;

  unsigned char* flags = (unsigned char*)(ws + 0);          // 32 KB
  int* counts = (int*)(ws + 32768);
  int* segidx = (int*)(ws + 65536);                         // 128 KB
  unsigned short* Hh0  = (unsigned short*)(ws + 1 * MB);    // 1 MB
  unsigned short* Hl0  = (unsigned short*)(ws + 2 * MB);    // 1 MB
  unsigned short* Hh1  = (unsigned short*)(ws + 3 * MB);    // 1 MB
  unsigned short* Hl1  = (unsigned short*)(ws + 4 * MB);    // 1 MB
  float* Cb            = (float*)(ws + 5 * MB);             // 2 MB
  unsigned short* WhhH = (unsigned short*)(ws + 7 * MB);    // 2 MB
  unsigned short* WhhL = (unsigned short*)(ws + 9 * MB);    // 2 MB
  unsigned short* WxH  = (unsigned short*)(ws + 11 * MB);   // 2 MB
  float* bsum          = (float*)(ws + 13 * MB);            // 8 KB
  unsigned short* W1t0 = (unsigned short*)(ws + 13 * MB + 262144);
  unsigned short* W1t1 = (unsigned short*)(ws + 13 * MB + 2 * 262144);
  unsigned short* W1t2 = (unsigned short*)(ws + 13 * MB + 3 * 262144);
  unsigned short* xhi  = (unsigned short*)(ws + 14 * MB);   // 32 MB
  unsigned short* gx   = (unsigned short*)(ws + 46 * MB);   // 128 MB -> ends 174 MB
  float* h1buf         = (float*)(ws + 46 * MB);            // 32 MB overlay on gx (dead before k_gx)

  hipLaunchKernelGGL(k_prep, dim3(4096), dim3(256), 0, stream,
                     x, Wih, Whh, bih, bhh, W1, out, xhi, WhhH, WhhL, WxH,
                     bsum, W1t0, W1t1, W1t2);
  hipLaunchKernelGGL(k_bnd1, dim3(512, 4), dim3(256), 0, stream, x, W1t0, W1t1, W1t2, b1, h1buf);
  hipLaunchKernelGGL(k_log, dim3(1024), dim3(256), 0, stream, h1buf, W2, b2, out, flags);
  hipLaunchKernelGGL(k_seg, dim3(8), dim3(256), 0, stream, flags, segidx, counts, out);
  hipLaunchKernelGGL(k_gx, dim3(256, 16), dim3(512), 0, stream, xhi, WxH, gx);
  hipLaunchKernelGGL(k_cell0, dim3(2048), dim3(256), 0, stream, gx, bsum, flags, segidx, Hh0, Hl0, Cb, out);
  for (int s = 1; s < 32; ++s) {
    const unsigned short* HhR = ((s - 1) & 1) ? Hh1 : Hh0;
    const unsigned short* HlR = ((s - 1) & 1) ? Hl1 : Hl0;
    unsigned short* HhW = (s & 1) ? Hh1 : Hh0;
    unsigned short* HlW = (s & 1) ? Hl1 : Hl0;
    hipLaunchKernelGGL(k_step2, dim3(512), dim3(256), 0, stream,
                       gx, WhhH, WhhL, HhR, HlR, HhW, HlW, Cb, bsum, flags, segidx, out, s);
  }
  hipLaunchKernelGGL(k_tail, dim3(32), dim3(256), 0, stream,
                     gx, WhhH, WhhL, Hh1, Hl1, Cb, bsum, flags, segidx, out);
  hipLaunchKernelGGL(k_fb, dim3(8), dim3(256), 0, stream, x, counts, out);
}

// Round 14
// 751.213 us; speedup vs baseline: 1.0955x; 1.0022x over previous
//
#include <hip/hip_runtime.h>
#include <math.h>

#define B 8
#define T 4096
#define D 512
#define H1 256
#define R 1024                      // B * NCH chunk-rows
#define BIDX_OFF ((size_t)B*T*D)          // 16777216
#define LOG_OFF  ((size_t)B*T*D + B*T)    // 16809984

typedef __attribute__((ext_vector_type(8))) short short8;
typedef __attribute__((ext_vector_type(4))) float f32x4;

__device__ inline unsigned short f2bf_hi(float f) {
  unsigned u = __float_as_uint(f);
  u += 0x7FFF + ((u >> 16) & 1);   // round-to-nearest-even bf16
  return (unsigned short)(u >> 16);
}
__device__ inline float bf2f(unsigned short b) {
  return __uint_as_float(((unsigned)b) << 16);
}
__device__ inline float sigm(float v) { return 1.f / (1.f + expf(-v)); }

// ---------------- prep: zero out, xhi bf16, W splits (gate-interleaved), W1 3-term, bsum ----------------
__global__ __launch_bounds__(256) void k_prep(const float* __restrict__ x,
                                              const float* __restrict__ Wih,
                                              const float* __restrict__ Whh,
                                              const float* __restrict__ bih,
                                              const float* __restrict__ bhh,
                                              const float* __restrict__ W1,
                                              float* __restrict__ out,
                                              unsigned short* __restrict__ xhi,
                                              unsigned short* __restrict__ WhhH,
                                              unsigned short* __restrict__ WhhL,
                                              unsigned short* __restrict__ WxH,
                                              float* __restrict__ bsum,
                                              unsigned short* __restrict__ W1t0,
                                              unsigned short* __restrict__ W1t1,
                                              unsigned short* __restrict__ W1t2) {
  int gid = blockIdx.x * 256 + threadIdx.x;   // 1,048,576 threads
  float4 z4 = make_float4(0.f, 0.f, 0.f, 0.f);
  // J0: zero padded output (64 MB)
  float4* o4 = (float4*)out;
#pragma unroll
  for (int i = 0; i < 4; ++i) o4[(size_t)i * 1048576 + gid] = z4;
  // J2: xhi bf16 (16 elems per thread)
  {
    const float* xs = x + (size_t)gid * 16;
    unsigned short hv[16];
#pragma unroll
    for (int q = 0; q < 4; ++q) {
      float4 v = *(const float4*)(xs + q * 4);
      hv[q * 4 + 0] = f2bf_hi(v.x); hv[q * 4 + 1] = f2bf_hi(v.y);
      hv[q * 4 + 2] = f2bf_hi(v.z); hv[q * 4 + 3] = f2bf_hi(v.w);
    }
    uint4 p0, p1;
    p0.x = (unsigned)hv[0] | ((unsigned)hv[1] << 16);  p0.y = (unsigned)hv[2] | ((unsigned)hv[3] << 16);
    p0.z = (unsigned)hv[4] | ((unsigned)hv[5] << 16);  p0.w = (unsigned)hv[6] | ((unsigned)hv[7] << 16);
    p1.x = (unsigned)hv[8] | ((unsigned)hv[9] << 16);  p1.y = (unsigned)hv[10] | ((unsigned)hv[11] << 16);
    p1.z = (unsigned)hv[12] | ((unsigned)hv[13] << 16); p1.w = (unsigned)hv[14] | ((unsigned)hv[15] << 16);
    *(uint4*)(xhi + (size_t)gid * 16) = p0;
    *(uint4*)(xhi + (size_t)gid * 16 + 8) = p1;
  }
  // J3: W splits, n' = 4d+g (gate-interleaved rows), K=512
  {
    int n = gid >> 9, k = gid & 511;
    int d = n >> 2, g = n & 3;
    size_t oo = (size_t)(g * 512 + d) * 512 + k;
    float wx = Wih[oo], wh = Whh[oo];
    WxH[(size_t)n * 512 + k] = f2bf_hi(wx);
    unsigned short hh = f2bf_hi(wh);
    WhhH[(size_t)n * 512 + k] = hh;
    WhhL[(size_t)n * 512 + k] = f2bf_hi(wh - bf2f(hh));
    if (k == 0) bsum[n] = bih[g * 512 + d] + bhh[g * 512 + d];
  }
  // J4: W1 3-term (8 elems per thread, first 16384 threads)
  if (gid < 16384) {
    int base = gid * 8;
    float4 a = *(const float4*)(W1 + base);
    float4 b = *(const float4*)(W1 + base + 4);
    float fv[8] = {a.x, a.y, a.z, a.w, b.x, b.y, b.z, b.w};
    unsigned short t0[8], t1[8], t2[8];
#pragma unroll
    for (int j = 0; j < 8; ++j) {
      unsigned short h0 = f2bf_hi(fv[j]);
      float r1 = fv[j] - bf2f(h0);
      unsigned short h1v = f2bf_hi(r1);
      float r2 = r1 - bf2f(h1v);
      t0[j] = h0; t1[j] = h1v; t2[j] = f2bf_hi(r2);
    }
    uint4 p0, p1, p2;
    p0.x = (unsigned)t0[0] | ((unsigned)t0[1] << 16); p0.y = (unsigned)t0[2] | ((unsigned)t0[3] << 16);
    p0.z = (unsigned)t0[4] | ((unsigned)t0[5] << 16); p0.w = (unsigned)t0[6] | ((unsigned)t0[7] << 16);
    p1.x = (unsigned)t1[0] | ((unsigned)t1[1] << 16); p1.y = (unsigned)t1[2] | ((unsigned)t1[3] << 16);
    p1.z = (unsigned)t1[4] | ((unsigned)t1[5] << 16); p1.w = (unsigned)t1[6] | ((unsigned)t1[7] << 16);
    p2.x = (unsigned)t2[0] | ((unsigned)t2[1] << 16); p2.y = (unsigned)t2[2] | ((unsigned)t2[3] << 16);
    p2.z = (unsigned)t2[4] | ((unsigned)t2[5] << 16); p2.w = (unsigned)t2[6] | ((unsigned)t2[7] << 16);
    *(uint4*)(W1t0 + base) = p0;
    *(uint4*)(W1t1 + base) = p1;
    *(uint4*)(W1t2 + base) = p2;
  }
}

// ---------------- boundary GEMM1 via MFMA, 3-term split ----------------
// grid (4, 512): x = n-panel (W1 terms pin per-XCD L2), y = m (x streams once)
__global__ __launch_bounds__(256) void k_bnd1(const float* __restrict__ x,
                                              const unsigned short* __restrict__ T0,
                                              const unsigned short* __restrict__ T1,
                                              const unsigned short* __restrict__ T2,
                                              const float* __restrict__ b1,
                                              float* __restrict__ h1out) {
  __shared__ unsigned short A0[64][48], A1[64][48], A2[64][48];
  __shared__ unsigned short B0[64][48], B1[64][48], B2[64][48];
  int bm = blockIdx.y, bnn = blockIdx.x;
  int tid = threadIdx.x;
  int arow = tid >> 2, ak0 = (tid & 3) * 8;
  const float* xrow = x + (size_t)(bm * 64 + arow) * 512;
  size_t wro = (size_t)(bnn * 64 + arow) * 512;

  int w = tid >> 6, l = tid & 63;
  int wm = w >> 1, wn = w & 1;
  int lrow = l & 15, lk = (l >> 4) * 8;

  f32x4 acc[2][2];
#pragma unroll
  for (int i = 0; i < 2; ++i)
#pragma unroll
    for (int j = 0; j < 2; ++j) acc[i][j] = (f32x4)(0.f);

  for (int kb = 0; kb < 512; kb += 32) {
    float4 a0v = *(const float4*)(xrow + kb + ak0);
    float4 a1v = *(const float4*)(xrow + kb + ak0 + 4);
    float fv[8] = {a0v.x, a0v.y, a0v.z, a0v.w, a1v.x, a1v.y, a1v.z, a1v.w};
    unsigned short s0[8], s1[8], s2[8];
#pragma unroll
    for (int j = 0; j < 8; ++j) {
      unsigned short h0 = f2bf_hi(fv[j]);
      float r1 = fv[j] - bf2f(h0);
      unsigned short h1v = f2bf_hi(r1);
      float r2 = r1 - bf2f(h1v);
      s0[j] = h0; s1[j] = h1v; s2[j] = f2bf_hi(r2);
    }
    uint4 p;
    p.x = (unsigned)s0[0] | ((unsigned)s0[1] << 16); p.y = (unsigned)s0[2] | ((unsigned)s0[3] << 16);
    p.z = (unsigned)s0[4] | ((unsigned)s0[5] << 16); p.w = (unsigned)s0[6] | ((unsigned)s0[7] << 16);
    *(uint4*)&A0[arow][ak0] = p;
    p.x = (unsigned)s1[0] | ((unsigned)s1[1] << 16); p.y = (unsigned)s1[2] | ((unsigned)s1[3] << 16);
    p.z = (unsigned)s1[4] | ((unsigned)s1[5] << 16); p.w = (unsigned)s1[6] | ((unsigned)s1[7] << 16);
    *(uint4*)&A1[arow][ak0] = p;
    p.x = (unsigned)s2[0] | ((unsigned)s2[1] << 16); p.y = (unsigned)s2[2] | ((unsigned)s2[3] << 16);
    p.z = (unsigned)s2[4] | ((unsigned)s2[5] << 16); p.w = (unsigned)s2[6] | ((unsigned)s2[7] << 16);
    *(uint4*)&A2[arow][ak0] = p;

    *(uint4*)&B0[arow][ak0] = *(const uint4*)(T0 + wro + kb + ak0);
    *(uint4*)&B1[arow][ak0] = *(const uint4*)(T1 + wro + kb + ak0);
    *(uint4*)&B2[arow][ak0] = *(const uint4*)(T2 + wro + kb + ak0);
    __syncthreads();

    short8 a0f[2], a1f[2], a2f[2], b0f[2], b1f[2], b2f[2];
#pragma unroll
    for (int fi = 0; fi < 2; ++fi) {
      a0f[fi] = *(const short8*)&A0[wm * 32 + fi * 16 + lrow][lk];
      a1f[fi] = *(const short8*)&A1[wm * 32 + fi * 16 + lrow][lk];
      a2f[fi] = *(const short8*)&A2[wm * 32 + fi * 16 + lrow][lk];
      b0f[fi] = *(const short8*)&B0[wn * 32 + fi * 16 + lrow][lk];
      b1f[fi] = *(const short8*)&B1[wn * 32 + fi * 16 + lrow][lk];
      b2f[fi] = *(const short8*)&B2[wn * 32 + fi * 16 + lrow][lk];
    }
#pragma unroll
    for (int fi = 0; fi < 2; ++fi)
#pragma unroll
      for (int fj = 0; fj < 2; ++fj) {
        acc[fi][fj] = __builtin_amdgcn_mfma_f32_16x16x32_bf16(a0f[fi], b0f[fj], acc[fi][fj], 0, 0, 0);
        acc[fi][fj] = __builtin_amdgcn_mfma_f32_16x16x32_bf16(a0f[fi], b1f[fj], acc[fi][fj], 0, 0, 0);
        acc[fi][fj] = __builtin_amdgcn_mfma_f32_16x16x32_bf16(a1f[fi], b0f[fj], acc[fi][fj], 0, 0, 0);
        acc[fi][fj] = __builtin_amdgcn_mfma_f32_16x16x32_bf16(a1f[fi], b1f[fj], acc[fi][fj], 0, 0, 0);
        acc[fi][fj] = __builtin_amdgcn_mfma_f32_16x16x32_bf16(a0f[fi], b2f[fj], acc[fi][fj], 0, 0, 0);
        acc[fi][fj] = __builtin_amdgcn_mfma_f32_16x16x32_bf16(a2f[fi], b0f[fj], acc[fi][fj], 0, 0, 0);
      }
    __syncthreads();
  }
#pragma unroll
  for (int fi = 0; fi < 2; ++fi)
#pragma unroll
    for (int fj = 0; fj < 2; ++fj) {
      int rrow = bm * 64 + wm * 32 + fi * 16 + (l >> 4) * 4;
      int rcol = bnn * 64 + wn * 32 + fj * 16 + lrow;
      float bv = b1[rcol];
#pragma unroll
      for (int reg = 0; reg < 4; ++reg) {
        float v = acc[fi][fj][reg] + bv;
        float ge = 0.5f * v * (1.0f + erff(v * 0.70710678118654752f));
        h1out[(size_t)(rrow + reg) * H1 + rcol] = ge;
      }
    }
}

// ---------------- logits + flags (f32 exact path) ----------------
__global__ __launch_bounds__(256) void k_log(const float* __restrict__ h1,
                                             const float* __restrict__ W2,
                                             const float* __restrict__ b2,
                                             float* __restrict__ out,
                                             unsigned char* __restrict__ flags) {
  int tid = threadIdx.x;
  int row = blockIdx.x * 32 + (tid >> 3);
  int part = tid & 7;
  const float* hr = h1 + (size_t)row * H1 + part * 32;
  const float* w0 = W2 + part * 32;
  const float* w1 = W2 + H1 + part * 32;
  float s0 = 0.f, s1 = 0.f;
#pragma unroll
  for (int q = 0; q < 8; ++q) {
    float4 hv = *(const float4*)(hr + q * 4);
    float4 w0v = *(const float4*)(w0 + q * 4);
    float4 w1v = *(const float4*)(w1 + q * 4);
    s0 = fmaf(hv.x, w0v.x, fmaf(hv.y, w0v.y, fmaf(hv.z, w0v.z, fmaf(hv.w, w0v.w, s0))));
    s1 = fmaf(hv.x, w1v.x, fmaf(hv.y, w1v.y, fmaf(hv.z, w1v.z, fmaf(hv.w, w1v.w, s1))));
  }
#pragma unroll
  for (int off = 4; off >= 1; off >>= 1) {
    s0 += __shfl_xor(s0, off);
    s1 += __shfl_xor(s1, off);
  }
  if (part == 0) {
    float l0 = s0 + b2[0], l1 = s1 + b2[1];
    out[LOG_OFF + (size_t)row * 2]     = l0;
    out[LOG_OFF + (size_t)row * 2 + 1] = l1;
    int t = row & (T - 1);
    bool forced = (((t & 31) == 0) && t != 0) || (t == T - 1);
    flags[row] = (forced || (l1 > l0)) ? 1 : 0;
  }
}

// ---------------- per-batch segmentation scan ----------------
__global__ __launch_bounds__(256) void k_seg(unsigned char* __restrict__ flags,
                                             int* __restrict__ segidx,
                                             int* __restrict__ counts,
                                             float* __restrict__ out) {
  int b = blockIdx.x, tid = threadIdx.x;
  __shared__ int sc[256];
  const int PER = T / 256;
  int base = tid * PER;
  bool em[PER];
  unsigned char prev = (tid == 0) ? 0 : (unsigned char)(flags[b * T + base - 1] & 1);
  int cnt = 0;
  for (int i = 0; i < PER; ++i) {
    int t = base + i;
    unsigned char cur = flags[b * T + t] & 1;
    bool reset = (t == 0) || (prev != 0);
    bool e = (cur != 0) && !reset;
    em[i] = e;
    cnt += e ? 1 : 0;
    flags[b * T + t] = (unsigned char)(cur | (reset ? 2 : 0) | (e ? 4 : 0));
    prev = cur;
  }
  sc[tid] = cnt;
  __syncthreads();
  for (int off = 1; off < 256; off <<= 1) {
    int v = (tid >= off) ? sc[tid - off] : 0;
    __syncthreads();
    sc[tid] += v;
    __syncthreads();
  }
  int total = sc[255];
  int run = sc[tid] - cnt;
  for (int i = 0; i < PER; ++i) {
    if (em[i]) { segidx[b * T + base + i] = run; run++; }
  }
  for (int j = tid; j < T; j += 256) out[BIDX_OFF + (size_t)b * T + j] = -1.0f;
  __syncthreads();
  run = sc[tid] - cnt;
  for (int i = 0; i < PER; ++i) {
    if (em[i]) { out[BIDX_OFF + (size_t)b * T + run] = (float)(base + i); run++; }
  }
  if (tid == 0) counts[b] = total;
}

// ---- gx = xhi @ WxH^T, M=32768 N=2048 K=512, 128x128 tile, BK=32, 512 threads ----
// grid (16, 256): x = n-panel -> each XCD pins W panels {x, x+8} in L2; xhi streams once.
__global__ __launch_bounds__(512) void k_gx(const unsigned short* __restrict__ xhi,
                                            const unsigned short* __restrict__ WxH,
                                            unsigned short* __restrict__ gx) {
  __shared__ unsigned short As[128][40], Bs[128][40];
  __shared__ unsigned short Cs[64][136];
  int m0 = blockIdx.y * 128, n0 = blockIdx.x * 128;
  int tid = threadIdx.x;
  int row = tid >> 2, col0 = (tid & 3) * 8;
  const unsigned short* asrc = xhi + (size_t)(m0 + row) * 512 + col0;
  const unsigned short* bsrc = WxH + (size_t)(n0 + row) * 512 + col0;

  int w = tid >> 6, l = tid & 63;
  int wm = w >> 2, wn = w & 3;
  int lrow = l & 15, lk = (l >> 4) * 8;

  f32x4 acc[4][2];
#pragma unroll
  for (int i = 0; i < 4; ++i)
#pragma unroll
    for (int j = 0; j < 2; ++j) acc[i][j] = (f32x4)(0.f);

  uint4 rA = *(const uint4*)asrc;
  uint4 rB = *(const uint4*)bsrc;

  for (int it = 0; it < 16; ++it) {
    *(uint4*)&As[row][col0] = rA;
    *(uint4*)&Bs[row][col0] = rB;
    __syncthreads();
    if (it < 15) {
      int ko = (it + 1) * 32;
      rA = *(const uint4*)(asrc + ko);
      rB = *(const uint4*)(bsrc + ko);
    }
    short8 af[4], bf[2];
#pragma unroll
    for (int fi = 0; fi < 4; ++fi)
      af[fi] = *(const short8*)&As[wm * 64 + fi * 16 + lrow][lk];
#pragma unroll
    for (int fj = 0; fj < 2; ++fj)
      bf[fj] = *(const short8*)&Bs[wn * 32 + fj * 16 + lrow][lk];
#pragma unroll
    for (int fi = 0; fi < 4; ++fi)
#pragma unroll
      for (int fj = 0; fj < 2; ++fj)
        acc[fi][fj] = __builtin_amdgcn_mfma_f32_16x16x32_bf16(af[fi], bf[fj], acc[fi][fj], 0, 0, 0);
    __syncthreads();
  }

#pragma unroll
  for (int h = 0; h < 2; ++h) {
    if (wm == h) {
#pragma unroll
      for (int fi = 0; fi < 4; ++fi)
#pragma unroll
        for (int fj = 0; fj < 2; ++fj) {
          int lr = fi * 16 + (l >> 4) * 4;
          int lc = wn * 32 + fj * 16 + lrow;
#pragma unroll
          for (int reg = 0; reg < 4; ++reg)
            Cs[lr + reg][lc] = f2bf_hi(acc[fi][fj][reg]);
        }
    }
    __syncthreads();
    int crow = tid >> 3, c0 = (tid & 7) * 16;
    size_t gbase = (size_t)(m0 + h * 64 + crow) * 2048 + n0 + c0;
    *(uint4*)(gx + gbase)     = *(uint4*)&Cs[crow][c0];
    *(uint4*)(gx + gbase + 8) = *(uint4*)&Cs[crow][c0 + 8];
    __syncthreads();
  }
}

// ---- s=0 cell-only: H,C are zero -> gates = gx + bsum; writes H buf0 ----
__global__ __launch_bounds__(256) void k_cell0(const unsigned short* __restrict__ gx,
                                               const float* __restrict__ bsum,
                                               const unsigned char* __restrict__ flags,
                                               const int* __restrict__ segidx,
                                               unsigned short* __restrict__ Hhi,
                                               unsigned short* __restrict__ Hlo,
                                               float* __restrict__ Cb,
                                               float* __restrict__ out) {
  int id = blockIdx.x * 256 + threadIdx.x;   // 524288 = 1024 x 512
  int rr = id >> 9, d = id & 511;
  int ch = rr & 127, bb = rr >> 7;
  int t = ch ? (32 * ch + 1) : 0;
  uint2 gp = *(const uint2*)(gx + ((size_t)(bb * T + t) * 2048 + 4 * d));
  float4 bsv = *(const float4*)&bsum[4 * d];
  float gi_ = bf2f((unsigned short)(gp.x & 0xffff)) + bsv.x;
  float gz_ = bf2f((unsigned short)(gp.y & 0xffff)) + bsv.z;
  float go_ = bf2f((unsigned short)(gp.y >> 16)) + bsv.w;
  float c = sigm(gi_) * tanhf(gz_);
  float h = sigm(go_) * tanhf(c);
  unsigned char fl = flags[bb * T + t];
  if (fl & 4) {
    int si = segidx[bb * T + t];
    out[(size_t)(bb * T + si) * D + d] = h;
  }
  bool isb = (fl & 1) != 0;
  float he = isb ? 0.f : h;
  float ce = isb ? 0.f : c;
  Cb[(size_t)rr * D + d] = ce;
  unsigned short hh = f2bf_hi(he);
  Hhi[(size_t)rr * D + d] = hh;
  Hlo[(size_t)rr * D + d] = f2bf_hi(he - bf2f(hh));
}

// ---- per-step (s=1..31): H-only GEMM K=512 (3-product) + cell with gx ----
// r13 version (BK=64, Ct aliased, 36.9 KB LDS, 4 blocks/CU) -- converged structure.
__global__ __launch_bounds__(256) void k_step2(const unsigned short* __restrict__ gx,
                                               const unsigned short* __restrict__ WhhH,
                                               const unsigned short* __restrict__ WhhL,
                                               const unsigned short* __restrict__ HhR,
                                               const unsigned short* __restrict__ HlR,
                                               unsigned short* __restrict__ HhW,
                                               unsigned short* __restrict__ HlW,
                                               float* __restrict__ Cb,
                                               const float* __restrict__ bsum,
                                               const unsigned char* __restrict__ flags,
                                               const int* __restrict__ segidx,
                                               float* __restrict__ out, int s) {
  __shared__ __align__(16) char smem[36864];
  unsigned short (*Ah)[72] = (unsigned short(*)[72])smem;             // 9216 B
  unsigned short (*Al)[72] = (unsigned short(*)[72])(smem + 9216);    // 9216 B
  unsigned short (*Bh)[72] = (unsigned short(*)[72])(smem + 18432);   // 9216 B
  unsigned short (*Bl)[72] = (unsigned short(*)[72])(smem + 27648);   // 9216 B
  float (*Ct)[68] = (float(*)[68])smem;                               // 17408 B alias (dead staging)

  int id = blockIdx.x;
  int bm = (id & 7) * 2 + (id >> 8);
  int bn = (id >> 3) & 31;
  int tid = threadIdx.x;
  int row = tid >> 2, col0 = (tid & 3) * 16;
  int ra = bm * 64 + row;
  const unsigned short* ah_src = HhR + (size_t)ra * D;
  const unsigned short* al_src = HlR + (size_t)ra * D;
  const unsigned short* bh_src = WhhH + (size_t)(bn * 64 + row) * D;
  const unsigned short* bl_src = WhhL + (size_t)(bn * 64 + row) * D;

  int w = tid >> 6, l = tid & 63;
  int wm = w >> 1, wn = w & 1;
  int lrow = l & 15, lk = (l >> 4) * 8;

  f32x4 acc[2][2];
#pragma unroll
  for (int i = 0; i < 2; ++i)
#pragma unroll
    for (int j = 0; j < 2; ++j) acc[i][j] = (f32x4)(0.f);

  uint4 rAh0 = *(const uint4*)(ah_src + col0), rAh1 = *(const uint4*)(ah_src + col0 + 8);
  uint4 rAl0 = *(const uint4*)(al_src + col0), rAl1 = *(const uint4*)(al_src + col0 + 8);
  uint4 rBh0 = *(const uint4*)(bh_src + col0), rBh1 = *(const uint4*)(bh_src + col0 + 8);
  uint4 rBl0 = *(const uint4*)(bl_src + col0), rBl1 = *(const uint4*)(bl_src + col0 + 8);

  for (int kk = 0; kk < 8; ++kk) {
    *(uint4*)&Ah[row][col0] = rAh0;  *(uint4*)&Ah[row][col0 + 8] = rAh1;
    *(uint4*)&Al[row][col0] = rAl0;  *(uint4*)&Al[row][col0 + 8] = rAl1;
    *(uint4*)&Bh[row][col0] = rBh0;  *(uint4*)&Bh[row][col0 + 8] = rBh1;
    *(uint4*)&Bl[row][col0] = rBl0;  *(uint4*)&Bl[row][col0 + 8] = rBl1;
    __syncthreads();
    if (kk < 7) {
      int ko = (kk + 1) * 64 + col0;
      rAh0 = *(const uint4*)(ah_src + ko); rAh1 = *(const uint4*)(ah_src + ko + 8);
      rAl0 = *(const uint4*)(al_src + ko); rAl1 = *(const uint4*)(al_src + ko + 8);
      rBh0 = *(const uint4*)(bh_src + ko); rBh1 = *(const uint4*)(bh_src + ko + 8);
      rBl0 = *(const uint4*)(bl_src + ko); rBl1 = *(const uint4*)(bl_src + ko + 8);
    }
#pragma unroll
    for (int ks = 0; ks < 2; ++ks) {
      short8 ah0 = *(const short8*)&Ah[wm * 32 + lrow][ks * 32 + lk];
      short8 ah1 = *(const short8*)&Ah[wm * 32 + 16 + lrow][ks * 32 + lk];
      short8 al0 = *(const short8*)&Al[wm * 32 + lrow][ks * 32 + lk];
      short8 al1 = *(const short8*)&Al[wm * 32 + 16 + lrow][ks * 32 + lk];
      short8 bh0 = *(const short8*)&Bh[wn * 32 + lrow][ks * 32 + lk];
      short8 bh1 = *(const short8*)&Bh[wn * 32 + 16 + lrow][ks * 32 + lk];
      short8 bl0 = *(const short8*)&Bl[wn * 32 + lrow][ks * 32 + lk];
      short8 bl1 = *(const short8*)&Bl[wn * 32 + 16 + lrow][ks * 32 + lk];
      acc[0][0] = __builtin_amdgcn_mfma_f32_16x16x32_bf16(ah0, bh0, acc[0][0], 0, 0, 0);
      acc[0][1] = __builtin_amdgcn_mfma_f32_16x16x32_bf16(ah0, bh1, acc[0][1], 0, 0, 0);
      acc[1][0] = __builtin_amdgcn_mfma_f32_16x16x32_bf16(ah1, bh0, acc[1][0], 0, 0, 0);
      acc[1][1] = __builtin_amdgcn_mfma_f32_16x16x32_bf16(ah1, bh1, acc[1][1], 0, 0, 0);
      acc[0][0] = __builtin_amdgcn_mfma_f32_16x16x32_bf16(ah0, bl0, acc[0][0], 0, 0, 0);
      acc[0][1] = __builtin_amdgcn_mfma_f32_16x16x32_bf16(ah0, bl1, acc[0][1], 0, 0, 0);
      acc[1][0] = __builtin_amdgcn_mfma_f32_16x16x32_bf16(ah1, bl0, acc[1][0], 0, 0, 0);
      acc[1][1] = __builtin_amdgcn_mfma_f32_16x16x32_bf16(ah1, bl1, acc[1][1], 0, 0, 0);
      acc[0][0] = __builtin_amdgcn_mfma_f32_16x16x32_bf16(al0, bh0, acc[0][0], 0, 0, 0);
      acc[0][1] = __builtin_amdgcn_mfma_f32_16x16x32_bf16(al0, bh1, acc[0][1], 0, 0, 0);
      acc[1][0] = __builtin_amdgcn_mfma_f32_16x16x32_bf16(al1, bh0, acc[1][0], 0, 0, 0);
      acc[1][1] = __builtin_amdgcn_mfma_f32_16x16x32_bf16(al1, bh1, acc[1][1], 0, 0, 0);
    }
    __syncthreads();   // final iteration's barrier protects the Ct alias below
  }

  // stash acc tile into aliased Ct (all staging reads completed before last barrier)
#pragma unroll
  for (int fi = 0; fi < 2; ++fi)
#pragma unroll
    for (int fj = 0; fj < 2; ++fj) {
      int crow = wm * 32 + fi * 16 + (l >> 4) * 4;
      int ccol = wn * 32 + fj * 16 + lrow;
#pragma unroll
      for (int reg = 0; reg < 4; ++reg)
        Ct[crow + reg][ccol] = acc[fi][fj][reg];
    }
  __syncthreads();

  int d_loc = tid & 15, rb = tid >> 4;
  int d_g = bn * 16 + d_loc;
  float4 bsv = *(const float4*)&bsum[(size_t)4 * d_g];
#pragma unroll
  for (int j = 0; j < 4; ++j) {
    int r_loc = rb + 16 * j;
    int r = bm * 64 + r_loc;
    int ch = r & 127, bb = r >> 7;
    int len = (ch == 0) ? 33 : ((ch == 127) ? 31 : 32);
    if (s >= len) continue;
    int t = (ch ? (32 * ch + 1) : 0) + s;
    unsigned char fl = flags[bb * T + t];
    float4 g = *(float4*)&Ct[r_loc][4 * d_loc];
    uint2 gp = *(const uint2*)(gx + ((size_t)(bb * T + t) * 2048 + 4 * d_g));
    float gi = g.x + bsv.x + bf2f((unsigned short)(gp.x & 0xffff));
    float gf = g.y + bsv.y + bf2f((unsigned short)(gp.x >> 16));
    float gz = g.z + bsv.z + bf2f((unsigned short)(gp.y & 0xffff));
    float go = g.w + bsv.w + bf2f((unsigned short)(gp.y >> 16));
    float cp = Cb[(size_t)r * D + d_g];
    float c = sigm(gf) * cp + sigm(gi) * tanhf(gz);
    float h = sigm(go) * tanhf(c);
    if (fl & 4) {
      int si = segidx[bb * T + t];
      out[(size_t)(bb * T + si) * D + d_g] = h;
    }
    bool isb = (fl & 1) != 0;
    float he = isb ? 0.f : h;
    float ce = isb ? 0.f : c;
    Cb[(size_t)r * D + d_g] = ce;
    unsigned short hh = f2bf_hi(he);
    HhW[(size_t)r * D + d_g] = hh;
    HlW[(size_t)r * D + d_g] = f2bf_hi(he - bf2f(hh));
  }
}

// ---- s=32 tail: only ch=0 rows (8 rows); reads H buf1 (written at s=31) ----
__global__ __launch_bounds__(256) void k_tail(const unsigned short* __restrict__ gx,
                                              const unsigned short* __restrict__ WhhH,
                                              const unsigned short* __restrict__ WhhL,
                                              const unsigned short* __restrict__ Hhi,
                                              const unsigned short* __restrict__ Hlo,
                                              const float* __restrict__ Cb,
                                              const float* __restrict__ bsum,
                                              const unsigned char* __restrict__ flags,
                                              const int* __restrict__ segidx,
                                              float* __restrict__ out) {
  __shared__ float hsh[512];
  __shared__ float gsh[128][4];
  int bb = blockIdx.x >> 2, q = blockIdx.x & 3;
  int r = bb * 128;             // ch = 0
  int tid = threadIdx.x;
  for (int i = tid; i < 512; i += 256)
    hsh[i] = bf2f(Hhi[(size_t)r * 512 + i]) + bf2f(Hlo[(size_t)r * 512 + i]);
  __syncthreads();
  int dd_loc = tid >> 1;
  int dd = q * 128 + dd_loc;
  int pair = tid & 1;
#pragma unroll
  for (int gg = 0; gg < 2; ++gg) {
    int n = 4 * dd + 2 * pair + gg;
    const unsigned short* wh = WhhH + (size_t)n * 512;
    const unsigned short* wl = WhhL + (size_t)n * 512;
    float sacc = 0.f;
    for (int k = 0; k < 512; k += 8) {
      uint4 ph = *(const uint4*)(wh + k);
      uint4 pl = *(const uint4*)(wl + k);
      unsigned pu[4] = {ph.x, ph.y, ph.z, ph.w};
      unsigned lu[4] = {pl.x, pl.y, pl.z, pl.w};
#pragma unroll
      for (int j = 0; j < 4; ++j) {
        float w0 = bf2f((unsigned short)(pu[j] & 0xffff)) + bf2f((unsigned short)(lu[j] & 0xffff));
        float w1 = bf2f((unsigned short)(pu[j] >> 16)) + bf2f((unsigned short)(lu[j] >> 16));
        sacc = fmaf(w0, hsh[k + 2 * j], sacc);
        sacc = fmaf(w1, hsh[k + 2 * j + 1], sacc);
      }
    }
    unsigned short gxv = gx[(size_t)(bb * T + 32) * 2048 + n];
    gsh[dd_loc][2 * pair + gg] = sacc + bf2f(gxv) + bsum[n];
  }
  __syncthreads();
  if (pair == 0) {
    unsigned char fl = flags[bb * T + 32];
    float gi = gsh[dd_loc][0], gf = gsh[dd_loc][1], gz = gsh[dd_loc][2], go = gsh[dd_loc][3];
    float cp = Cb[(size_t)r * 512 + dd];
    float c = sigm(gf) * cp + sigm(gi) * tanhf(gz);
    float h = sigm(go) * tanhf(c);
    if (fl & 4) {
      int si = segidx[bb * T + 32];
      out[(size_t)(bb * T + si) * D + dd] = h;
    }
  }
}

// ---------------- fallback: no segments emitted -> mean over time ----------------
__global__ __launch_bounds__(256) void k_fb(const float* __restrict__ x,
                                            const int* __restrict__ counts,
                                            float* __restrict__ out) {
  int b = blockIdx.x;
  if (counts[b] != 0) return;
  int tid = threadIdx.x;
  for (int d = tid; d < D; d += 256) {
    float sum = 0.f;
    for (int t = 0; t < T; ++t) sum += x[(size_t)(b * T + t) * D + d];
    out[(size_t)(b * T) * D + d] = sum / (float)T;
  }
  if (tid == 0) out[BIDX_OFF + (size_t)b * T] = (float)(T - 1);
}

// ==================== LAUNCH ====================

extern "C" void kernel_launch(void* const* d_in, const int* in_sizes, int n_in,
                              void* d_out, int out_size, void* d_ws, size_t ws_size,
                              hipStream_t stream) {
  const float* x   = (const float*)d_in[0];
  const float* W1  = (const float*)d_in[1];
  const float* b1  = (const float*)d_in[2];
  const float* W2  = (const float*)d_in[3];
  const float* b2  = (const float*)d_in[4];
  const float* Wih = (const float*)d_in[5];
  const float* Whh = (const float*)d_in[6];
  const float* bih = (const float*)d_in[7];
  const float* bhh = (const float*)d_in[8];
  float* out = (float*)d_out;
  char* ws = (char*)d_ws;
  const size_t MB = 1 << 20;

  unsigned char* flags = (unsigned char*)(ws + 0);          // 32 KB
  int* counts = (int*)(ws + 32768);
  int* segidx = (int*)(ws + 65536);                         // 128 KB
  unsigned short* Hh0  = (unsigned short*)(ws + 1 * MB);    // 1 MB
  unsigned short* Hl0  = (unsigned short*)(ws + 2 * MB);    // 1 MB
  unsigned short* Hh1  = (unsigned short*)(ws + 3 * MB);    // 1 MB
  unsigned short* Hl1  = (unsigned short*)(ws + 4 * MB);    // 1 MB
  float* Cb            = (float*)(ws + 5 * MB);             // 2 MB
  unsigned short* WhhH = (unsigned short*)(ws + 7 * MB);    // 2 MB
  unsigned short* WhhL = (unsigned short*)(ws + 9 * MB);    // 2 MB
  unsigned short* WxH  = (unsigned short*)(ws + 11 * MB);   // 2 MB
  float* bsum          = (float*)(ws + 13 * MB);            // 8 KB
  unsigned short* W1t0 = (unsigned short*)(ws + 13 * MB + 262144);
  unsigned short* W1t1 = (unsigned short*)(ws + 13 * MB + 2 * 262144);
  unsigned short* W1t2 = (unsigned short*)(ws + 13 * MB + 3 * 262144);
  unsigned short* xhi  = (unsigned short*)(ws + 14 * MB);   // 32 MB
  unsigned short* gx   = (unsigned short*)(ws + 46 * MB);   // 128 MB -> ends 174 MB
  float* h1buf         = (float*)(ws + 46 * MB);            // 32 MB overlay on gx (dead before k_gx)

  hipLaunchKernelGGL(k_prep, dim3(4096), dim3(256), 0, stream,
                     x, Wih, Whh, bih, bhh, W1, out, xhi, WhhH, WhhL, WxH,
                     bsum, W1t0, W1t1, W1t2);
  hipLaunchKernelGGL(k_bnd1, dim3(4, 512), dim3(256), 0, stream, x, W1t0, W1t1, W1t2, b1, h1buf);
  hipLaunchKernelGGL(k_log, dim3(1024), dim3(256), 0, stream, h1buf, W2, b2, out, flags);
  hipLaunchKernelGGL(k_seg, dim3(8), dim3(256), 0, stream, flags, segidx, counts, out);
  hipLaunchKernelGGL(k_gx, dim3(16, 256), dim3(512), 0, stream, xhi, WxH, gx);
  hipLaunchKernelGGL(k_cell0, dim3(2048), dim3(256), 0, stream, gx, bsum, flags, segidx, Hh0, Hl0, Cb, out);
  for (int s = 1; s < 32; ++s) {
    const unsigned short* HhR = ((s - 1) & 1) ? Hh1 : Hh0;
    const unsigned short* HlR = ((s - 1) & 1) ? Hl1 : Hl0;
    unsigned short* HhW = (s & 1) ? Hh1 : Hh0;
    unsigned short* HlW = (s & 1) ? Hl1 : Hl0;
    hipLaunchKernelGGL(k_step2, dim3(512), dim3(256), 0, stream,
                       gx, WhhH, WhhL, HhR, HlR, HhW, HlW, Cb, bsum, flags, segidx, out, s);
  }
  hipLaunchKernelGGL(k_tail, dim3(32), dim3(256), 0, stream,
                     gx, WhhH, WhhL, Hh1, Hl1, Cb, bsum, flags, segidx, out);
  hipLaunchKernelGGL(k_fb, dim3(8), dim3(256), 0, stream, x, counts, out);
}